// Round 6
// baseline (963.992 us; speedup 1.0000x reference)
//
#include <hip/hip_runtime.h>
#include <hip/hip_bf16.h>
#include <math.h>

#define B_SZ   32
#define NXX    16384
#define IN_DIM 3
#define DIM    64
#define JM     16
#define MODE   128
#define RANKK  4
#define FC_DIM 128
#define N_LAY  3

typedef __attribute__((ext_vector_type(8))) short bf16x8;
typedef __attribute__((ext_vector_type(4))) float f32x4;
typedef unsigned short u16;

__device__ __forceinline__ float gelu_exact(float v) {
    return 0.5f * v * (1.0f + erff(v * 0.70710678118654752f));
}
__device__ __forceinline__ float bf2f(u16 u) {
    return __uint_as_float((unsigned)u << 16);
}
__device__ __forceinline__ void split_bf16(float v, u16& h, u16& l) {
    __hip_bfloat16 bh = __float2bfloat16(v);
    float fh = __bfloat162float(bh);
    __hip_bfloat16 bl = __float2bfloat16(v - fh);
    h = *(u16*)&bh;
    l = *(u16*)&bl;
}

// ---------------------------------------------------------------------------
__global__ __launch_bounds__(256) void k_zero(float* __restrict__ p, int n) {
    int i = blockIdx.x * 256 + threadIdx.x;
    if (i < n) p[i] = 0.f;
}

// H[j,k,l] = D_out[j,k]*D_in[j,l]*product[k,l] + sum_r A[j,r,k]*Bm[j,r,l]
__global__ __launch_bounds__(256) void k_build_H(
        const float* __restrict__ Dout, const float* __restrict__ Din,
        const float* __restrict__ product, const float* __restrict__ A,
        const float* __restrict__ Bm, float* __restrict__ H) {
    int idx = blockIdx.x * 256 + threadIdx.x;
    int j = idx >> 14;
    int k = (idx >> 7) & 127;
    int l = idx & 127;
    float v = Dout[j * MODE + k] * Din[j * MODE + l] * product[k * MODE + l];
#pragma unroll
    for (int r = 0; r < RANKK; ++r)
        v += A[(j * RANKK + r) * MODE + k] * Bm[(j * RANKK + r) * MODE + l];
    H[idx] = v;
}

// bases (fp32 [x][k]) -> FRAG-MAJOR hi/lo planes:
//   Bf[(k>>3)*131072 + x*8 + (k&7)]   grid 8192 x 256.  (lo may be null)
__global__ __launch_bounds__(256) void k_setup_bases(
        const float* __restrict__ bases, u16* __restrict__ bh, u16* __restrict__ bl) {
    int idx = blockIdx.x * 256 + threadIdx.x;
    int x = idx >> 7, k = idx & 127;
    u16 h, l;
    split_bf16(bases[idx], h, l);
    size_t off = (size_t)(k >> 3) * 131072 + (size_t)x * 8 + (k & 7);
    bh[off] = h;
    if (bl) bl[off] = l;
}

// wbT[l][x] = wbases[x][l], split hi/lo.  grid (512, 4) x 256, LDS-tiled.
__global__ __launch_bounds__(256) void k_setup_wbT(
        const float* __restrict__ wb, u16* __restrict__ Th, u16* __restrict__ Tl) {
    __shared__ float tile[32][33];
    int bx = blockIdx.x, bl = blockIdx.y;
    int t = threadIdx.x;
    int i = t >> 5, jj = t & 31;
#pragma unroll
    for (int r = 0; r < 4; ++r)
        tile[i + r * 8][jj] = wb[(size_t)(bx * 32 + i + r * 8) * MODE + bl * 32 + jj];
    __syncthreads();
#pragma unroll
    for (int r = 0; r < 4; ++r) {
        int l = bl * 32 + i + r * 8;
        int x = bx * 32 + jj;
        u16 h, lo;
        split_bf16(tile[jj][i + r * 8], h, lo);
        Th[(size_t)l * NXX + x] = h;
        Tl[(size_t)l * NXX + x] = lo;
    }
}

// W1T[f*64+c] = W1[c*128+f] hi/lo.  grid 32 x 256
__global__ __launch_bounds__(256) void k_setup_w1t(
        const float* __restrict__ W1, u16* __restrict__ wh, u16* __restrict__ wl) {
    int i = blockIdx.x * 256 + threadIdx.x;
    int f = i >> 6, c = i & 63;
    u16 h, l;
    split_bf16(W1[c * FC_DIM + f], h, l);
    wh[i] = h; wl[i] = l;
}

// fc0 v2: h[b,x,c] = sum_d x[b,x,d]*W0[d,c] + b0[c]
// 256 thr: thread t -> (x_local = t>>3, c8 = (t&7)*8): 8 channels, ushort8
// coalesced stores.  grid (512, 32) x 256.
__global__ __launch_bounds__(256) void k_fc0(
        const float* __restrict__ x, const float* __restrict__ W0,
        const float* __restrict__ b0, u16* __restrict__ hh, u16* __restrict__ hl) {
    __shared__ float w0s[IN_DIM * DIM + DIM];
    int t = threadIdx.x;
    if (t < IN_DIM * DIM) w0s[t] = W0[t];
    if (t < DIM) w0s[IN_DIM * DIM + t] = b0[t];
    __syncthreads();
    int b = blockIdx.y;
    int xi = blockIdx.x * 32 + (t >> 3);
    int c8 = (t & 7) * 8;
    const float* xp = x + ((size_t)b * NXX + xi) * IN_DIM;
    float x0 = xp[0], x1 = xp[1], x2 = xp[2];
    ushort4 uh0, uh1, ul0, ul1;
    u16 rh[8], rl[8];
#pragma unroll
    for (int i = 0; i < 8; ++i) {
        int c = c8 + i;
        float v = x0 * w0s[c] + x1 * w0s[DIM + c] + x2 * w0s[2 * DIM + c]
                + w0s[3 * DIM + c];
        split_bf16(v, rh[i], rl[i]);
    }
    size_t o = ((size_t)(b << 14) + xi) * 64 + c8;
    uh0 = make_ushort4(rh[0], rh[1], rh[2], rh[3]);
    uh1 = make_ushort4(rh[4], rh[5], rh[6], rh[7]);
    ul0 = make_ushort4(rl[0], rl[1], rl[2], rl[3]);
    ul1 = make_ushort4(rl[4], rl[5], rl[6], rl[7]);
    *(ushort4*)(hh + o) = uh0;
    *(ushort4*)(hh + o + 4) = uh1;
    *(ushort4*)(hl + o) = ul0;
    *(ushort4*)(hl + o + 4) = ul1;
}

// ---------------------------------------------------------------------------
// Spectral via MFMA: xh[b][c][l] += sum_x h[b][x][c] * wbases[x][l]
// (unchanged from R5: rotation-swizzled LDS transpose, split-K atomics)
#define SPAD 72
__global__ __launch_bounds__(256, 2) void k_spectral_mfma(
        const u16* __restrict__ Hh, const u16* __restrict__ Hl,
        const u16* __restrict__ Wh, const u16* __restrict__ Wl,
        float* __restrict__ xh) {
    __shared__ u16 Ash[64 * SPAD];
    __shared__ u16 Asl[64 * SPAD];
    int t = threadIdx.x;
    int wave = t >> 6, lane = t & 63, quad = lane >> 4, l16 = lane & 15;
    int b = blockIdx.x;
    int x0 = blockIdx.y * 1024;
    int cq = (t & 15) * 4;
    int xq = (t >> 4) * 4;
    int colw = (xq + ((t & 7) << 3)) & 63;
    const u16* srch = Hh + ((size_t)(b << 14) + x0 + xq) * 64 + cq;
    const u16* srcl = Hl + ((size_t)(b << 14) + x0 + xq) * 64 + cq;
    int l0 = wave * 32;
    const u16* w0h = Wh + (size_t)(l0 + l16) * NXX + x0;
    const u16* w1h = Wh + (size_t)(l0 + 16 + l16) * NXX + x0;
    const u16* w0l = Wl + (size_t)(l0 + l16) * NXX + x0;
    const u16* w1l = Wl + (size_t)(l0 + 16 + l16) * NXX + x0;
    f32x4 acc[4][2] = {};
    for (int kt = 0; kt < 1024; kt += 64) {
        __syncthreads();
        {
            const u16* s = srch + (size_t)kt * 64;
            ushort4 r0 = *(const ushort4*)(s);
            ushort4 r1 = *(const ushort4*)(s + 64);
            ushort4 r2 = *(const ushort4*)(s + 128);
            ushort4 r3 = *(const ushort4*)(s + 192);
            *(ushort4*)&Ash[(cq + 0) * SPAD + colw] = make_ushort4(r0.x, r1.x, r2.x, r3.x);
            *(ushort4*)&Ash[(cq + 1) * SPAD + colw] = make_ushort4(r0.y, r1.y, r2.y, r3.y);
            *(ushort4*)&Ash[(cq + 2) * SPAD + colw] = make_ushort4(r0.z, r1.z, r2.z, r3.z);
            *(ushort4*)&Ash[(cq + 3) * SPAD + colw] = make_ushort4(r0.w, r1.w, r2.w, r3.w);
            s = srcl + (size_t)kt * 64;
            r0 = *(const ushort4*)(s);
            r1 = *(const ushort4*)(s + 64);
            r2 = *(const ushort4*)(s + 128);
            r3 = *(const ushort4*)(s + 192);
            *(ushort4*)&Asl[(cq + 0) * SPAD + colw] = make_ushort4(r0.x, r1.x, r2.x, r3.x);
            *(ushort4*)&Asl[(cq + 1) * SPAD + colw] = make_ushort4(r0.y, r1.y, r2.y, r3.y);
            *(ushort4*)&Asl[(cq + 2) * SPAD + colw] = make_ushort4(r0.z, r1.z, r2.z, r3.z);
            *(ushort4*)&Asl[(cq + 3) * SPAD + colw] = make_ushort4(r0.w, r1.w, r2.w, r3.w);
        }
        __syncthreads();
#pragma unroll
        for (int k0 = 0; k0 < 64; k0 += 32) {
            bf16x8 afh[4], afl[4];
#pragma unroll
            for (int ct = 0; ct < 4; ++ct) {
                int rr = ct * 16 + l16;
                int ro = rr * SPAD + (((k0 + quad * 8) + (((rr >> 2) & 7) << 3)) & 63);
                afh[ct] = *(const bf16x8*)&Ash[ro];
                afl[ct] = *(const bf16x8*)&Asl[ro];
            }
            int go = kt + k0 + quad * 8;
            bf16x8 b0h = *(const bf16x8*)(w0h + go);
            bf16x8 b0l = *(const bf16x8*)(w0l + go);
            bf16x8 b1h = *(const bf16x8*)(w1h + go);
            bf16x8 b1l = *(const bf16x8*)(w1l + go);
#pragma unroll
            for (int ct = 0; ct < 4; ++ct) {
                acc[ct][0] = __builtin_amdgcn_mfma_f32_16x16x32_bf16(afh[ct], b0l, acc[ct][0], 0, 0, 0);
                acc[ct][0] = __builtin_amdgcn_mfma_f32_16x16x32_bf16(afl[ct], b0h, acc[ct][0], 0, 0, 0);
                acc[ct][0] = __builtin_amdgcn_mfma_f32_16x16x32_bf16(afh[ct], b0h, acc[ct][0], 0, 0, 0);
                acc[ct][1] = __builtin_amdgcn_mfma_f32_16x16x32_bf16(afh[ct], b1l, acc[ct][1], 0, 0, 0);
                acc[ct][1] = __builtin_amdgcn_mfma_f32_16x16x32_bf16(afl[ct], b1h, acc[ct][1], 0, 0, 0);
                acc[ct][1] = __builtin_amdgcn_mfma_f32_16x16x32_bf16(afh[ct], b1h, acc[ct][1], 0, 0, 0);
            }
        }
    }
    float* xb = xh + (size_t)(b << 6) * 128;
#pragma unroll
    for (int ct = 0; ct < 4; ++ct)
#pragma unroll
        for (int lt = 0; lt < 2; ++lt)
#pragma unroll
            for (int r = 0; r < 4; ++r)
                atomicAdd(xb + (size_t)(ct * 16 + quad * 4 + r) * 128 + l0 + lt * 16 + l16,
                          acc[ct][lt][r]);
}

// ---------------------------------------------------------------------------
// Fused H-mix + channel contraction.  grid (32, 16) x 256
__global__ __launch_bounds__(256) void k_hmix(
        const float* __restrict__ xh, const float* __restrict__ H,
        const float* __restrict__ Wsp, float* __restrict__ y, int lay) {
    __shared__ float xs[DIM][132];
    __shared__ float Ts[DIM][MODE];
    __shared__ float Ws[DIM][DIM];
    int t = threadIdx.x;
    int b = blockIdx.x;
    int j = blockIdx.y;
    const float* xb = xh + (size_t)b * DIM * MODE;
    for (int idx = t; idx < DIM * MODE; idx += 256)
        xs[idx >> 7][idx & 127] = xb[idx];
    const float* Wl = Wsp + (size_t)lay * DIM * DIM * JM + j;
    for (int idx = t; idx < DIM * DIM; idx += 256)
        Ws[idx >> 6][idx & 63] = Wl[(size_t)idx * JM];
    __syncthreads();
    {
        int k4 = (t & 31) * 4;
        int i0 = (t >> 5) * 8;
        float acc[8][4] = {};
        const float* Hbase = H + ((size_t)j * MODE + k4) * MODE;
        for (int l = 0; l < MODE; l += 4) {
            float4 hv0 = *(const float4*)(Hbase + 0 * MODE + l);
            float4 hv1 = *(const float4*)(Hbase + 1 * MODE + l);
            float4 hv2 = *(const float4*)(Hbase + 2 * MODE + l);
            float4 hv3 = *(const float4*)(Hbase + 3 * MODE + l);
#pragma unroll
            for (int ii = 0; ii < 8; ++ii) {
                float4 xv = *(const float4*)&xs[i0 + ii][l];
                acc[ii][0] += hv0.x * xv.x + hv0.y * xv.y + hv0.z * xv.z + hv0.w * xv.w;
                acc[ii][1] += hv1.x * xv.x + hv1.y * xv.y + hv1.z * xv.z + hv1.w * xv.w;
                acc[ii][2] += hv2.x * xv.x + hv2.y * xv.y + hv2.z * xv.z + hv2.w * xv.w;
                acc[ii][3] += hv3.x * xv.x + hv3.y * xv.y + hv3.z * xv.z + hv3.w * xv.w;
            }
        }
#pragma unroll
        for (int ii = 0; ii < 8; ++ii)
            *(float4*)&Ts[i0 + ii][k4] = make_float4(acc[ii][0], acc[ii][1], acc[ii][2], acc[ii][3]);
    }
    __syncthreads();
    {
        int k = t & 127;
        int o0 = (t >> 7) * 32;
        float acc2[32] = {};
        for (int i = 0; i < DIM; ++i) {
            float tv = Ts[i][k];
            const float* wr = &Ws[i][o0];
#pragma unroll
            for (int o4 = 0; o4 < 32; o4 += 4) {
                float4 wv = *(const float4*)(wr + o4);
                acc2[o4 + 0] += wv.x * tv;
                acc2[o4 + 1] += wv.y * tv;
                acc2[o4 + 2] += wv.z * tv;
                acc2[o4 + 3] += wv.w * tv;
            }
        }
        float* yp = y + ((size_t)b * DIM + o0) * MODE + k;
#pragma unroll
        for (int o = 0; o < 32; ++o)
            atomicAdd(yp + (size_t)o * MODE, acc2[o]);
    }
}

// A buffer in FRAG-MAJOR layout (see R5).  grid (32) x 256
__global__ __launch_bounds__(256) void k_build_A(
        const float* __restrict__ y, const float* __restrict__ Wconv,
        u16* __restrict__ Ah, u16* __restrict__ Al, int lay) {
    int b = blockIdx.x;
    for (int idx = threadIdx.x; idx < 12288; idx += 256) {
        int i = idx & 7, l16 = (idx >> 3) & 15, quad = (idx >> 7) & 3,
            ot = (idx >> 9) & 3, ks = idx >> 11;
        int o = ot * 16 + l16;
        int k = ks * 32 + quad * 8 + i;
        float v = (k < 128) ? y[((size_t)b * DIM + o) * MODE + k]
                            : Wconv[(size_t)lay * DIM * DIM + o * DIM + (k - 128)];
        u16 h, l;
        split_bf16(v, h, l);
        size_t off = (size_t)b * 12288 + idx;
        Ah[off] = h; Al[off] = l;
    }
}

// ---------------------------------------------------------------------------
// inv_conv v3: h' = act(A(64x192) @ B(192 x 128x) + bconv), in-place on h.
// When do_mlp: instead of writing h' back, compute the final MLP from the
// LDS-staged h' tile and write `out` directly (lay 2 fusion — h never
// round-trips through HBM).
// grid (32 b, 128 xt) x 256 (4 waves; wave = 64o x 32x).
#define CPAD 72
template <bool BLO>
__global__ __launch_bounds__(256, 2) void k_inv_conv_mfma(
        const u16* __restrict__ Afh, const u16* __restrict__ Afl,
        const u16* __restrict__ Bfh, const u16* __restrict__ Bfl,
        u16* __restrict__ Hh, u16* __restrict__ Hl,
        const float* __restrict__ bconv, int lay, int do_act, int do_mlp,
        const u16* __restrict__ W1h, const u16* __restrict__ W1l,
        const float* __restrict__ b1, const float* __restrict__ W2,
        const float* __restrict__ b2, float* __restrict__ out) {
    __shared__ u16 hsh[128 * CPAD];
    __shared__ u16 hsl[128 * CPAD];
    int t = threadIdx.x;
    int wave = t >> 6, lane = t & 63, quad = lane >> 4, l16 = lane & 15;
    int b = blockIdx.x;
    int x0 = blockIdx.y * 128;
    // stage h tile [128 x][64 c] -> LDS (coalesced 16B chunks)
#pragma unroll
    for (int it = 0; it < 4; ++it) {
        int idx = it * 256 + t;
        int row = idx >> 3, c8 = (idx & 7) * 8;
        size_t src = ((size_t)(b << 14) + x0 + row) * 64 + c8;
        *(bf16x8*)&hsh[row * CPAD + c8] = *(const bf16x8*)(Hh + src);
        *(bf16x8*)&hsl[row * CPAD + c8] = *(const bf16x8*)(Hl + src);
    }
    __syncthreads();

    int xw = wave * 32;
    const u16* afb_h = Afh + (size_t)b * 12288;
    const u16* afb_l = Afl + (size_t)b * 12288;
    f32x4 acc[4][2] = {};
#pragma unroll
    for (int ks = 0; ks < 6; ++ks) {
        bf16x8 afh[4], afl[4], bfh[2], bfl[2];
#pragma unroll
        for (int ot = 0; ot < 4; ++ot) {
            size_t ao = (size_t)(((ks * 4 + ot) * 4 + quad) * 16 + l16) * 8;
            afh[ot] = *(const bf16x8*)(afb_h + ao);
            afl[ot] = *(const bf16x8*)(afb_l + ao);
        }
        bool haslo = BLO || ks >= 4;
#pragma unroll
        for (int x2 = 0; x2 < 2; ++x2) {
            int xl = xw + x2 * 16 + l16;
            if (ks < 4) {
                size_t bo = (size_t)((ks * 4 + quad) * 16384 + x0 + xl) * 8;
                bfh[x2] = *(const bf16x8*)(Bfh + bo);
                if (BLO) bfl[x2] = *(const bf16x8*)(Bfl + bo);
            } else {
                int ko = (ks - 4) * 32 + quad * 8;
                bfh[x2] = *(const bf16x8*)&hsh[xl * CPAD + ko];
                bfl[x2] = *(const bf16x8*)&hsl[xl * CPAD + ko];
            }
        }
#pragma unroll
        for (int ot = 0; ot < 4; ++ot)
#pragma unroll
            for (int x2 = 0; x2 < 2; ++x2) {
                if (haslo)
                    acc[ot][x2] = __builtin_amdgcn_mfma_f32_16x16x32_bf16(afh[ot], bfl[x2], acc[ot][x2], 0, 0, 0);
                acc[ot][x2] = __builtin_amdgcn_mfma_f32_16x16x32_bf16(afl[ot], bfh[x2], acc[ot][x2], 0, 0, 0);
                acc[ot][x2] = __builtin_amdgcn_mfma_f32_16x16x32_bf16(afh[ot], bfh[x2], acc[ot][x2], 0, 0, 0);
            }
    }
    __syncthreads();   // all LDS h reads done -> reuse hsh/hsl for C staging

#pragma unroll
    for (int ot = 0; ot < 4; ++ot) {
        float4 bc = *(const float4*)(bconv + lay * DIM + ot * 16 + quad * 4);
#pragma unroll
        for (int x2 = 0; x2 < 2; ++x2) {
            int xl = xw + x2 * 16 + l16;
            float vr[4] = {acc[ot][x2][0] + bc.x, acc[ot][x2][1] + bc.y,
                           acc[ot][x2][2] + bc.z, acc[ot][x2][3] + bc.w};
            if (do_act) {
#pragma unroll
                for (int r = 0; r < 4; ++r) vr[r] = gelu_exact(vr[r]);
            }
            ushort4 uh, ul;
            split_bf16(vr[0], uh.x, ul.x);
            split_bf16(vr[1], uh.y, ul.y);
            split_bf16(vr[2], uh.z, ul.z);
            split_bf16(vr[3], uh.w, ul.w);
            *(ushort4*)&hsh[xl * CPAD + ot * 16 + quad * 4] = uh;
            *(ushort4*)&hsl[xl * CPAD + ot * 16 + quad * 4] = ul;
        }
    }
    __syncthreads();

    if (!do_mlp) {
        // write h' back to global (lay 0,1)
#pragma unroll
        for (int it = 0; it < 4; ++it) {
            int idx = it * 256 + t;
            int row = idx >> 3, c8 = (idx & 7) * 8;
            size_t dst = ((size_t)(b << 14) + x0 + row) * 64 + c8;
            *(bf16x8*)(Hh + dst) = *(const bf16x8*)&hsh[row * CPAD + c8];
            *(bf16x8*)(Hl + dst) = *(const bf16x8*)&hsl[row * CPAD + c8];
        }
        return;
    }

    // ---- fused final MLP (lay 2): out = gelu(h'@W1+b1)@W2 + b2 ----
#pragma unroll
    for (int x2 = 0; x2 < 2; ++x2) {
        bf16x8 ah[2], al[2];
#pragma unroll
        for (int ks = 0; ks < 2; ++ks) {
            int ro = (xw + x2 * 16 + l16) * CPAD + ks * 32 + quad * 8;
            ah[ks] = *(const bf16x8*)&hsh[ro];
            al[ks] = *(const bf16x8*)&hsl[ro];
        }
        float vo[4] = {0.f, 0.f, 0.f, 0.f};
#pragma unroll
        for (int ft = 0; ft < 8; ++ft) {
            f32x4 a2 = {};
#pragma unroll
            for (int ks = 0; ks < 2; ++ks) {
                size_t o = (size_t)(ft * 16 + l16) * 64 + ks * 32 + quad * 8;
                bf16x8 bh = *(const bf16x8*)(W1h + o);
                bf16x8 bl = *(const bf16x8*)(W1l + o);
                a2 = __builtin_amdgcn_mfma_f32_16x16x32_bf16(ah[ks], bl, a2, 0, 0, 0);
                a2 = __builtin_amdgcn_mfma_f32_16x16x32_bf16(al[ks], bh, a2, 0, 0, 0);
                a2 = __builtin_amdgcn_mfma_f32_16x16x32_bf16(ah[ks], bh, a2, 0, 0, 0);
            }
            float bb = b1[ft * 16 + l16];
            float w2 = W2[ft * 16 + l16];
#pragma unroll
            for (int r = 0; r < 4; ++r)
                vo[r] += gelu_exact(a2[r] + bb) * w2;
        }
#pragma unroll
        for (int r = 0; r < 4; ++r) {
            float v = vo[r];
            v += __shfl_xor(v, 1);
            v += __shfl_xor(v, 2);
            v += __shfl_xor(v, 4);
            v += __shfl_xor(v, 8);
            vo[r] = v;
        }
        if (l16 == 0) {
            float bb2 = b2[0];
            float4 o4 = make_float4(vo[0] + bb2, vo[1] + bb2, vo[2] + bb2, vo[3] + bb2);
            *(float4*)(out + (size_t)b * NXX + x0 + xw + x2 * 16 + quad * 4) = o4;
        }
    }
}

// ---------------------------------------------------------------------------
extern "C" void kernel_launch(void* const* d_in, const int* in_sizes, int n_in,
                              void* d_out, int out_size, void* d_ws, size_t ws_size,
                              hipStream_t stream) {
    const float* x      = (const float*)d_in[0];
    const float* bases  = (const float*)d_in[1];
    const float* wbases = (const float*)d_in[2];
    const float* product= (const float*)d_in[3];
    const float* Dout   = (const float*)d_in[4];
    const float* Din    = (const float*)d_in[5];
    const float* A      = (const float*)d_in[6];
    const float* Bm     = (const float*)d_in[7];
    const float* Wsp    = (const float*)d_in[8];
    const float* Wconv  = (const float*)d_in[9];
    const float* bconv  = (const float*)d_in[10];
    const float* W0     = (const float*)d_in[11];
    const float* b0     = (const float*)d_in[12];
    const float* W1     = (const float*)d_in[13];
    const float* b1     = (const float*)d_in[14];
    const float* W2     = (const float*)d_in[15];
    const float* b2     = (const float*)d_in[16];
    float* out = (float*)d_out;

    const size_t need_full    = 155746304;
    const size_t need_reduced = 151552000;
    bool full = ws_size >= need_full;
    if (!full && ws_size < need_reduced) {
        k_zero<<<dim3((out_size + 255) / 256), dim3(256), 0, stream>>>(out, out_size);
        return;
    }

    char* W = (char*)d_ws;
    size_t off = 0;
    auto alloc = [&](size_t bytes) { void* p = W + off; off += bytes; return p; };
    float* Hbuf     = (float*)alloc(1048576);
    u16*   bases_hi = (u16*)alloc(4194304);
    u16*   bases_lo = full ? (u16*)alloc(4194304) : nullptr;
    u16*   wbT_hi   = (u16*)alloc(4194304);
    u16*   wbT_lo   = (u16*)alloc(4194304);
    u16*   Abuf_hi  = (u16*)alloc(786432);
    u16*   Abuf_lo  = (u16*)alloc(786432);
    float* ybuf     = (float*)alloc(1048576);
    float* xh       = (float*)alloc(1048576);   // must follow ybuf (joint zeroing)
    u16*   h_hi     = (u16*)alloc(67108864);
    u16*   h_lo     = (u16*)alloc(67108864);
    u16*   w1t_hi   = (u16*)alloc(16384);
    u16*   w1t_lo   = (u16*)alloc(16384);

    k_build_H<<<dim3(1024), dim3(256), 0, stream>>>(Dout, Din, product, A, Bm, Hbuf);
    k_setup_bases<<<dim3(8192), dim3(256), 0, stream>>>(bases, bases_hi, bases_lo);
    k_setup_wbT<<<dim3(512, 4), dim3(256), 0, stream>>>(wbases, wbT_hi, wbT_lo);
    k_setup_w1t<<<dim3(32), dim3(256), 0, stream>>>(W1, w1t_hi, w1t_lo);
    k_fc0<<<dim3(512, B_SZ), dim3(256), 0, stream>>>(x, W0, b0, h_hi, h_lo);

    for (int lay = 0; lay < N_LAY; ++lay) {
        int last = (lay == N_LAY - 1);
        k_zero<<<dim3(2048), dim3(256), 0, stream>>>(ybuf, 524288);  // ybuf + xh
        k_spectral_mfma<<<dim3(B_SZ, 16), dim3(256), 0, stream>>>(
            h_hi, h_lo, wbT_hi, wbT_lo, xh);
        k_hmix<<<dim3(B_SZ, JM), dim3(256), 0, stream>>>(xh, Hbuf, Wsp, ybuf, lay);
        k_build_A<<<dim3(B_SZ), dim3(256), 0, stream>>>(ybuf, Wconv, Abuf_hi, Abuf_lo, lay);
        if (full)
            k_inv_conv_mfma<true><<<dim3(B_SZ, 128), dim3(256), 0, stream>>>(
                Abuf_hi, Abuf_lo, bases_hi, bases_lo, h_hi, h_lo,
                bconv, lay, last ? 0 : 1, last,
                w1t_hi, w1t_lo, b1, W2, b2, out);
        else
            k_inv_conv_mfma<false><<<dim3(B_SZ, 128), dim3(256), 0, stream>>>(
                Abuf_hi, Abuf_lo, bases_hi, bases_hi, h_hi, h_lo,
                bconv, lay, last ? 0 : 1, last,
                w1t_hi, w1t_lo, b1, W2, b2, out);
    }
}

// Round 7
// 838.669 us; speedup vs baseline: 1.1494x; 1.1494x over previous
//
#include <hip/hip_runtime.h>
#include <hip/hip_bf16.h>
#include <math.h>

#define B_SZ   32
#define NXX    16384
#define IN_DIM 3
#define DIM    64
#define JM     16
#define MODE   128
#define RANKK  4
#define FC_DIM 128
#define N_LAY  3

typedef __attribute__((ext_vector_type(8))) short bf16x8;
typedef __attribute__((ext_vector_type(4))) float f32x4;
typedef unsigned short u16;

__device__ __forceinline__ float gelu_exact(float v) {
    return 0.5f * v * (1.0f + erff(v * 0.70710678118654752f));
}
__device__ __forceinline__ float bf2f(u16 u) {
    return __uint_as_float((unsigned)u << 16);
}
__device__ __forceinline__ void split_bf16(float v, u16& h, u16& l) {
    __hip_bfloat16 bh = __float2bfloat16(v);
    float fh = __bfloat162float(bh);
    __hip_bfloat16 bl = __float2bfloat16(v - fh);
    h = *(u16*)&bh;
    l = *(u16*)&bl;
}

// ---------------------------------------------------------------------------
__global__ __launch_bounds__(256) void k_zero(float* __restrict__ p, int n) {
    int i = blockIdx.x * 256 + threadIdx.x;
    if (i < n) p[i] = 0.f;
}

// H[j,k,l] = D_out[j,k]*D_in[j,l]*product[k,l] + sum_r A[j,r,k]*Bm[j,r,l]
__global__ __launch_bounds__(256) void k_build_H(
        const float* __restrict__ Dout, const float* __restrict__ Din,
        const float* __restrict__ product, const float* __restrict__ A,
        const float* __restrict__ Bm, float* __restrict__ H) {
    int idx = blockIdx.x * 256 + threadIdx.x;
    int j = idx >> 14;
    int k = (idx >> 7) & 127;
    int l = idx & 127;
    float v = Dout[j * MODE + k] * Din[j * MODE + l] * product[k * MODE + l];
#pragma unroll
    for (int r = 0; r < RANKK; ++r)
        v += A[(j * RANKK + r) * MODE + k] * Bm[(j * RANKK + r) * MODE + l];
    H[idx] = v;
}

// bases (fp32 [x][k]) -> FRAG-MAJOR hi/lo planes:
//   Bf[(k>>3)*131072 + x*8 + (k&7)]   grid 8192 x 256.  (lo may be null)
__global__ __launch_bounds__(256) void k_setup_bases(
        const float* __restrict__ bases, u16* __restrict__ bh, u16* __restrict__ bl) {
    int idx = blockIdx.x * 256 + threadIdx.x;
    int x = idx >> 7, k = idx & 127;
    u16 h, l;
    split_bf16(bases[idx], h, l);
    size_t off = (size_t)(k >> 3) * 131072 + (size_t)x * 8 + (k & 7);
    bh[off] = h;
    if (bl) bl[off] = l;
}

// wbT[l][x] = wbases[x][l], split hi/lo.  grid (512, 4) x 256, LDS-tiled.
__global__ __launch_bounds__(256) void k_setup_wbT(
        const float* __restrict__ wb, u16* __restrict__ Th, u16* __restrict__ Tl) {
    __shared__ float tile[32][33];
    int bx = blockIdx.x, bl = blockIdx.y;
    int t = threadIdx.x;
    int i = t >> 5, jj = t & 31;
#pragma unroll
    for (int r = 0; r < 4; ++r)
        tile[i + r * 8][jj] = wb[(size_t)(bx * 32 + i + r * 8) * MODE + bl * 32 + jj];
    __syncthreads();
#pragma unroll
    for (int r = 0; r < 4; ++r) {
        int l = bl * 32 + i + r * 8;
        int x = bx * 32 + jj;
        u16 h, lo;
        split_bf16(tile[jj][i + r * 8], h, lo);
        Th[(size_t)l * NXX + x] = h;
        Tl[(size_t)l * NXX + x] = lo;
    }
}

// W1T[f*64+c] = W1[c*128+f] hi/lo.  grid 32 x 256
__global__ __launch_bounds__(256) void k_setup_w1t(
        const float* __restrict__ W1, u16* __restrict__ wh, u16* __restrict__ wl) {
    int i = blockIdx.x * 256 + threadIdx.x;
    int f = i >> 6, c = i & 63;
    u16 h, l;
    split_bf16(W1[c * FC_DIM + f], h, l);
    wh[i] = h; wl[i] = l;
}

// fc0: h[b,x,c] coalesced ushort8 stores.  grid (512, 32) x 256.
__global__ __launch_bounds__(256) void k_fc0(
        const float* __restrict__ x, const float* __restrict__ W0,
        const float* __restrict__ b0, u16* __restrict__ hh, u16* __restrict__ hl) {
    __shared__ float w0s[IN_DIM * DIM + DIM];
    int t = threadIdx.x;
    if (t < IN_DIM * DIM) w0s[t] = W0[t];
    if (t < DIM) w0s[IN_DIM * DIM + t] = b0[t];
    __syncthreads();
    int b = blockIdx.y;
    int xi = blockIdx.x * 32 + (t >> 3);
    int c8 = (t & 7) * 8;
    const float* xp = x + ((size_t)b * NXX + xi) * IN_DIM;
    float x0 = xp[0], x1 = xp[1], x2 = xp[2];
    u16 rh[8], rl[8];
#pragma unroll
    for (int i = 0; i < 8; ++i) {
        int c = c8 + i;
        float v = x0 * w0s[c] + x1 * w0s[DIM + c] + x2 * w0s[2 * DIM + c]
                + w0s[3 * DIM + c];
        split_bf16(v, rh[i], rl[i]);
    }
    size_t o = ((size_t)(b << 14) + xi) * 64 + c8;
    *(ushort4*)(hh + o)     = make_ushort4(rh[0], rh[1], rh[2], rh[3]);
    *(ushort4*)(hh + o + 4) = make_ushort4(rh[4], rh[5], rh[6], rh[7]);
    *(ushort4*)(hl + o)     = make_ushort4(rl[0], rl[1], rl[2], rl[3]);
    *(ushort4*)(hl + o + 4) = make_ushort4(rl[4], rl[5], rl[6], rl[7]);
}

// ---------------------------------------------------------------------------
// Spectral via MFMA (unchanged from R5).
#define SPAD 72
__global__ __launch_bounds__(256, 2) void k_spectral_mfma(
        const u16* __restrict__ Hh, const u16* __restrict__ Hl,
        const u16* __restrict__ Wh, const u16* __restrict__ Wl,
        float* __restrict__ xh) {
    __shared__ u16 Ash[64 * SPAD];
    __shared__ u16 Asl[64 * SPAD];
    int t = threadIdx.x;
    int wave = t >> 6, lane = t & 63, quad = lane >> 4, l16 = lane & 15;
    int b = blockIdx.x;
    int x0 = blockIdx.y * 1024;
    int cq = (t & 15) * 4;
    int xq = (t >> 4) * 4;
    int colw = (xq + ((t & 7) << 3)) & 63;
    const u16* srch = Hh + ((size_t)(b << 14) + x0 + xq) * 64 + cq;
    const u16* srcl = Hl + ((size_t)(b << 14) + x0 + xq) * 64 + cq;
    int l0 = wave * 32;
    const u16* w0h = Wh + (size_t)(l0 + l16) * NXX + x0;
    const u16* w1h = Wh + (size_t)(l0 + 16 + l16) * NXX + x0;
    const u16* w0l = Wl + (size_t)(l0 + l16) * NXX + x0;
    const u16* w1l = Wl + (size_t)(l0 + 16 + l16) * NXX + x0;
    f32x4 acc[4][2] = {};
    for (int kt = 0; kt < 1024; kt += 64) {
        __syncthreads();
        {
            const u16* s = srch + (size_t)kt * 64;
            ushort4 r0 = *(const ushort4*)(s);
            ushort4 r1 = *(const ushort4*)(s + 64);
            ushort4 r2 = *(const ushort4*)(s + 128);
            ushort4 r3 = *(const ushort4*)(s + 192);
            *(ushort4*)&Ash[(cq + 0) * SPAD + colw] = make_ushort4(r0.x, r1.x, r2.x, r3.x);
            *(ushort4*)&Ash[(cq + 1) * SPAD + colw] = make_ushort4(r0.y, r1.y, r2.y, r3.y);
            *(ushort4*)&Ash[(cq + 2) * SPAD + colw] = make_ushort4(r0.z, r1.z, r2.z, r3.z);
            *(ushort4*)&Ash[(cq + 3) * SPAD + colw] = make_ushort4(r0.w, r1.w, r2.w, r3.w);
            s = srcl + (size_t)kt * 64;
            r0 = *(const ushort4*)(s);
            r1 = *(const ushort4*)(s + 64);
            r2 = *(const ushort4*)(s + 128);
            r3 = *(const ushort4*)(s + 192);
            *(ushort4*)&Asl[(cq + 0) * SPAD + colw] = make_ushort4(r0.x, r1.x, r2.x, r3.x);
            *(ushort4*)&Asl[(cq + 1) * SPAD + colw] = make_ushort4(r0.y, r1.y, r2.y, r3.y);
            *(ushort4*)&Asl[(cq + 2) * SPAD + colw] = make_ushort4(r0.z, r1.z, r2.z, r3.z);
            *(ushort4*)&Asl[(cq + 3) * SPAD + colw] = make_ushort4(r0.w, r1.w, r2.w, r3.w);
        }
        __syncthreads();
#pragma unroll
        for (int k0 = 0; k0 < 64; k0 += 32) {
            bf16x8 afh[4], afl[4];
#pragma unroll
            for (int ct = 0; ct < 4; ++ct) {
                int rr = ct * 16 + l16;
                int ro = rr * SPAD + (((k0 + quad * 8) + (((rr >> 2) & 7) << 3)) & 63);
                afh[ct] = *(const bf16x8*)&Ash[ro];
                afl[ct] = *(const bf16x8*)&Asl[ro];
            }
            int go = kt + k0 + quad * 8;
            bf16x8 b0h = *(const bf16x8*)(w0h + go);
            bf16x8 b0l = *(const bf16x8*)(w0l + go);
            bf16x8 b1h = *(const bf16x8*)(w1h + go);
            bf16x8 b1l = *(const bf16x8*)(w1l + go);
#pragma unroll
            for (int ct = 0; ct < 4; ++ct) {
                acc[ct][0] = __builtin_amdgcn_mfma_f32_16x16x32_bf16(afh[ct], b0l, acc[ct][0], 0, 0, 0);
                acc[ct][0] = __builtin_amdgcn_mfma_f32_16x16x32_bf16(afl[ct], b0h, acc[ct][0], 0, 0, 0);
                acc[ct][0] = __builtin_amdgcn_mfma_f32_16x16x32_bf16(afh[ct], b0h, acc[ct][0], 0, 0, 0);
                acc[ct][1] = __builtin_amdgcn_mfma_f32_16x16x32_bf16(afh[ct], b1l, acc[ct][1], 0, 0, 0);
                acc[ct][1] = __builtin_amdgcn_mfma_f32_16x16x32_bf16(afl[ct], b1h, acc[ct][1], 0, 0, 0);
                acc[ct][1] = __builtin_amdgcn_mfma_f32_16x16x32_bf16(afh[ct], b1h, acc[ct][1], 0, 0, 0);
            }
        }
    }
    float* xb = xh + (size_t)(b << 6) * 128;
#pragma unroll
    for (int ct = 0; ct < 4; ++ct)
#pragma unroll
        for (int lt = 0; lt < 2; ++lt)
#pragma unroll
            for (int r = 0; r < 4; ++r)
                atomicAdd(xb + (size_t)(ct * 16 + quad * 4 + r) * 128 + l0 + lt * 16 + l16,
                          acc[ct][lt][r]);
}

// ---------------------------------------------------------------------------
// Fused H-mix + channel contraction.  grid (32, 16) x 256
__global__ __launch_bounds__(256) void k_hmix(
        const float* __restrict__ xh, const float* __restrict__ H,
        const float* __restrict__ Wsp, float* __restrict__ y, int lay) {
    __shared__ float xs[DIM][132];
    __shared__ float Ts[DIM][MODE];
    __shared__ float Ws[DIM][DIM];
    int t = threadIdx.x;
    int b = blockIdx.x;
    int j = blockIdx.y;
    const float* xb = xh + (size_t)b * DIM * MODE;
    for (int idx = t; idx < DIM * MODE; idx += 256)
        xs[idx >> 7][idx & 127] = xb[idx];
    const float* Wl = Wsp + (size_t)lay * DIM * DIM * JM + j;
    for (int idx = t; idx < DIM * DIM; idx += 256)
        Ws[idx >> 6][idx & 63] = Wl[(size_t)idx * JM];
    __syncthreads();
    {
        int k4 = (t & 31) * 4;
        int i0 = (t >> 5) * 8;
        float acc[8][4] = {};
        const float* Hbase = H + ((size_t)j * MODE + k4) * MODE;
        for (int l = 0; l < MODE; l += 4) {
            float4 hv0 = *(const float4*)(Hbase + 0 * MODE + l);
            float4 hv1 = *(const float4*)(Hbase + 1 * MODE + l);
            float4 hv2 = *(const float4*)(Hbase + 2 * MODE + l);
            float4 hv3 = *(const float4*)(Hbase + 3 * MODE + l);
#pragma unroll
            for (int ii = 0; ii < 8; ++ii) {
                float4 xv = *(const float4*)&xs[i0 + ii][l];
                acc[ii][0] += hv0.x * xv.x + hv0.y * xv.y + hv0.z * xv.z + hv0.w * xv.w;
                acc[ii][1] += hv1.x * xv.x + hv1.y * xv.y + hv1.z * xv.z + hv1.w * xv.w;
                acc[ii][2] += hv2.x * xv.x + hv2.y * xv.y + hv2.z * xv.z + hv2.w * xv.w;
                acc[ii][3] += hv3.x * xv.x + hv3.y * xv.y + hv3.z * xv.z + hv3.w * xv.w;
            }
        }
#pragma unroll
        for (int ii = 0; ii < 8; ++ii)
            *(float4*)&Ts[i0 + ii][k4] = make_float4(acc[ii][0], acc[ii][1], acc[ii][2], acc[ii][3]);
    }
    __syncthreads();
    {
        int k = t & 127;
        int o0 = (t >> 7) * 32;
        float acc2[32] = {};
        for (int i = 0; i < DIM; ++i) {
            float tv = Ts[i][k];
            const float* wr = &Ws[i][o0];
#pragma unroll
            for (int o4 = 0; o4 < 32; o4 += 4) {
                float4 wv = *(const float4*)(wr + o4);
                acc2[o4 + 0] += wv.x * tv;
                acc2[o4 + 1] += wv.y * tv;
                acc2[o4 + 2] += wv.z * tv;
                acc2[o4 + 3] += wv.w * tv;
            }
        }
        float* yp = y + ((size_t)b * DIM + o0) * MODE + k;
#pragma unroll
        for (int o = 0; o < 32; ++o)
            atomicAdd(yp + (size_t)o * MODE, acc2[o]);
    }
}

// A buffer in FRAG-MAJOR layout.  grid (32) x 256
__global__ __launch_bounds__(256) void k_build_A(
        const float* __restrict__ y, const float* __restrict__ Wconv,
        u16* __restrict__ Ah, u16* __restrict__ Al, int lay) {
    int b = blockIdx.x;
    for (int idx = threadIdx.x; idx < 12288; idx += 256) {
        int i = idx & 7, l16 = (idx >> 3) & 15, quad = (idx >> 7) & 3,
            ot = (idx >> 9) & 3, ks = idx >> 11;
        int o = ot * 16 + l16;
        int k = ks * 32 + quad * 8 + i;
        float v = (k < 128) ? y[((size_t)b * DIM + o) * MODE + k]
                            : Wconv[(size_t)lay * DIM * DIM + o * DIM + (k - 128)];
        u16 h, l;
        split_bf16(v, h, l);
        size_t off = (size_t)b * 12288 + idx;
        Ah[off] = h; Al[off] = l;
    }
}

// ---------------------------------------------------------------------------
// inv_conv v4: h' = act(A(64x192) @ B(192 x 128x) + bconv), in-place on h.
// DO_MLP is COMPILE-TIME: lay0/1 instantiate the lean kernel (no MLP regs ->
// R5's 80-VGPR codegen); lay2 instantiates the fused kernel (computes the
// final MLP from the LDS tile, skips the h writeback).
// grid (32 b, 128 xt) x 256 (4 waves; wave = 64o x 32x).
#define CPAD 72
template <bool BLO, bool DO_MLP>
__global__ __launch_bounds__(256, 2) void k_inv_conv_mfma(
        const u16* __restrict__ Afh, const u16* __restrict__ Afl,
        const u16* __restrict__ Bfh, const u16* __restrict__ Bfl,
        u16* __restrict__ Hh, u16* __restrict__ Hl,
        const float* __restrict__ bconv, int lay,
        const u16* __restrict__ W1h, const u16* __restrict__ W1l,
        const float* __restrict__ b1, const float* __restrict__ W2,
        const float* __restrict__ b2, float* __restrict__ out) {
    __shared__ u16 hsh[128 * CPAD];
    __shared__ u16 hsl[128 * CPAD];
    int t = threadIdx.x;
    int wave = t >> 6, lane = t & 63, quad = lane >> 4, l16 = lane & 15;
    int b = blockIdx.x;
    int x0 = blockIdx.y * 128;
#pragma unroll
    for (int it = 0; it < 4; ++it) {
        int idx = it * 256 + t;
        int row = idx >> 3, c8 = (idx & 7) * 8;
        size_t src = ((size_t)(b << 14) + x0 + row) * 64 + c8;
        *(bf16x8*)&hsh[row * CPAD + c8] = *(const bf16x8*)(Hh + src);
        *(bf16x8*)&hsl[row * CPAD + c8] = *(const bf16x8*)(Hl + src);
    }
    __syncthreads();

    int xw = wave * 32;
    const u16* afb_h = Afh + (size_t)b * 12288;
    const u16* afb_l = Afl + (size_t)b * 12288;
    f32x4 acc[4][2] = {};
#pragma unroll
    for (int ks = 0; ks < 6; ++ks) {
        bf16x8 afh[4], afl[4], bfh[2], bfl[2];
#pragma unroll
        for (int ot = 0; ot < 4; ++ot) {
            size_t ao = (size_t)(((ks * 4 + ot) * 4 + quad) * 16 + l16) * 8;
            afh[ot] = *(const bf16x8*)(afb_h + ao);
            afl[ot] = *(const bf16x8*)(afb_l + ao);
        }
        bool haslo = BLO || ks >= 4;
#pragma unroll
        for (int x2 = 0; x2 < 2; ++x2) {
            int xl = xw + x2 * 16 + l16;
            if (ks < 4) {
                size_t bo = (size_t)((ks * 4 + quad) * 16384 + x0 + xl) * 8;
                bfh[x2] = *(const bf16x8*)(Bfh + bo);
                if (BLO) bfl[x2] = *(const bf16x8*)(Bfl + bo);
            } else {
                int ko = (ks - 4) * 32 + quad * 8;
                bfh[x2] = *(const bf16x8*)&hsh[xl * CPAD + ko];
                bfl[x2] = *(const bf16x8*)&hsl[xl * CPAD + ko];
            }
        }
#pragma unroll
        for (int ot = 0; ot < 4; ++ot)
#pragma unroll
            for (int x2 = 0; x2 < 2; ++x2) {
                if (haslo)
                    acc[ot][x2] = __builtin_amdgcn_mfma_f32_16x16x32_bf16(afh[ot], bfl[x2], acc[ot][x2], 0, 0, 0);
                acc[ot][x2] = __builtin_amdgcn_mfma_f32_16x16x32_bf16(afl[ot], bfh[x2], acc[ot][x2], 0, 0, 0);
                acc[ot][x2] = __builtin_amdgcn_mfma_f32_16x16x32_bf16(afh[ot], bfh[x2], acc[ot][x2], 0, 0, 0);
            }
    }
    __syncthreads();   // all LDS h reads done -> reuse hsh/hsl for C staging

#pragma unroll
    for (int ot = 0; ot < 4; ++ot) {
        float4 bc = *(const float4*)(bconv + lay * DIM + ot * 16 + quad * 4);
#pragma unroll
        for (int x2 = 0; x2 < 2; ++x2) {
            int xl = xw + x2 * 16 + l16;
            float vr[4] = {acc[ot][x2][0] + bc.x, acc[ot][x2][1] + bc.y,
                           acc[ot][x2][2] + bc.z, acc[ot][x2][3] + bc.w};
            if (!DO_MLP) {   // gelu between layers; final layer has no act
#pragma unroll
                for (int r = 0; r < 4; ++r) vr[r] = gelu_exact(vr[r]);
            }
            ushort4 uh, ul;
            split_bf16(vr[0], uh.x, ul.x);
            split_bf16(vr[1], uh.y, ul.y);
            split_bf16(vr[2], uh.z, ul.z);
            split_bf16(vr[3], uh.w, ul.w);
            *(ushort4*)&hsh[xl * CPAD + ot * 16 + quad * 4] = uh;
            *(ushort4*)&hsl[xl * CPAD + ot * 16 + quad * 4] = ul;
        }
    }
    __syncthreads();

    if (!DO_MLP) {
#pragma unroll
        for (int it = 0; it < 4; ++it) {
            int idx = it * 256 + t;
            int row = idx >> 3, c8 = (idx & 7) * 8;
            size_t dst = ((size_t)(b << 14) + x0 + row) * 64 + c8;
            *(bf16x8*)(Hh + dst) = *(const bf16x8*)&hsh[row * CPAD + c8];
            *(bf16x8*)(Hl + dst) = *(const bf16x8*)&hsl[row * CPAD + c8];
        }
        return;
    }

    // ---- fused final MLP (lay 2 only): out = gelu(h'@W1+b1)@W2 + b2 ----
#pragma unroll
    for (int x2 = 0; x2 < 2; ++x2) {
        bf16x8 ah[2], al[2];
#pragma unroll
        for (int ks = 0; ks < 2; ++ks) {
            int ro = (xw + x2 * 16 + l16) * CPAD + ks * 32 + quad * 8;
            ah[ks] = *(const bf16x8*)&hsh[ro];
            al[ks] = *(const bf16x8*)&hsl[ro];
        }
        float vo[4] = {0.f, 0.f, 0.f, 0.f};
#pragma unroll
        for (int ft = 0; ft < 8; ++ft) {
            f32x4 a2 = {};
#pragma unroll
            for (int ks = 0; ks < 2; ++ks) {
                size_t o = (size_t)(ft * 16 + l16) * 64 + ks * 32 + quad * 8;
                bf16x8 bh = *(const bf16x8*)(W1h + o);
                bf16x8 bl = *(const bf16x8*)(W1l + o);
                a2 = __builtin_amdgcn_mfma_f32_16x16x32_bf16(ah[ks], bl, a2, 0, 0, 0);
                a2 = __builtin_amdgcn_mfma_f32_16x16x32_bf16(al[ks], bh, a2, 0, 0, 0);
                a2 = __builtin_amdgcn_mfma_f32_16x16x32_bf16(ah[ks], bh, a2, 0, 0, 0);
            }
            float bb = b1[ft * 16 + l16];
            float w2 = W2[ft * 16 + l16];
#pragma unroll
            for (int r = 0; r < 4; ++r)
                vo[r] += gelu_exact(a2[r] + bb) * w2;
        }
#pragma unroll
        for (int r = 0; r < 4; ++r) {
            float v = vo[r];
            v += __shfl_xor(v, 1);
            v += __shfl_xor(v, 2);
            v += __shfl_xor(v, 4);
            v += __shfl_xor(v, 8);
            vo[r] = v;
        }
        if (l16 == 0) {
            float bb2 = b2[0];
            float4 o4 = make_float4(vo[0] + bb2, vo[1] + bb2, vo[2] + bb2, vo[3] + bb2);
            *(float4*)(out + (size_t)b * NXX + x0 + xw + x2 * 16 + quad * 4) = o4;
        }
    }
}

// ---------------------------------------------------------------------------
extern "C" void kernel_launch(void* const* d_in, const int* in_sizes, int n_in,
                              void* d_out, int out_size, void* d_ws, size_t ws_size,
                              hipStream_t stream) {
    const float* x      = (const float*)d_in[0];
    const float* bases  = (const float*)d_in[1];
    const float* wbases = (const float*)d_in[2];
    const float* product= (const float*)d_in[3];
    const float* Dout   = (const float*)d_in[4];
    const float* Din    = (const float*)d_in[5];
    const float* A      = (const float*)d_in[6];
    const float* Bm     = (const float*)d_in[7];
    const float* Wsp    = (const float*)d_in[8];
    const float* Wconv  = (const float*)d_in[9];
    const float* bconv  = (const float*)d_in[10];
    const float* W0     = (const float*)d_in[11];
    const float* b0     = (const float*)d_in[12];
    const float* W1     = (const float*)d_in[13];
    const float* b1     = (const float*)d_in[14];
    const float* W2     = (const float*)d_in[15];
    const float* b2     = (const float*)d_in[16];
    float* out = (float*)d_out;

    const size_t need_full    = 155746304;
    const size_t need_reduced = 151552000;
    bool full = ws_size >= need_full;
    if (!full && ws_size < need_reduced) {
        k_zero<<<dim3((out_size + 255) / 256), dim3(256), 0, stream>>>(out, out_size);
        return;
    }

    char* W = (char*)d_ws;
    size_t off = 0;
    auto alloc = [&](size_t bytes) { void* p = W + off; off += bytes; return p; };
    float* Hbuf     = (float*)alloc(1048576);
    u16*   bases_hi = (u16*)alloc(4194304);
    u16*   bases_lo = full ? (u16*)alloc(4194304) : nullptr;
    u16*   wbT_hi   = (u16*)alloc(4194304);
    u16*   wbT_lo   = (u16*)alloc(4194304);
    u16*   Abuf_hi  = (u16*)alloc(786432);
    u16*   Abuf_lo  = (u16*)alloc(786432);
    float* ybuf     = (float*)alloc(1048576);
    float* xh       = (float*)alloc(1048576);   // must follow ybuf (joint zeroing)
    u16*   h_hi     = (u16*)alloc(67108864);
    u16*   h_lo     = (u16*)alloc(67108864);
    u16*   w1t_hi   = (u16*)alloc(16384);
    u16*   w1t_lo   = (u16*)alloc(16384);

    k_build_H<<<dim3(1024), dim3(256), 0, stream>>>(Dout, Din, product, A, Bm, Hbuf);
    k_setup_bases<<<dim3(8192), dim3(256), 0, stream>>>(bases, bases_hi, bases_lo);
    k_setup_wbT<<<dim3(512, 4), dim3(256), 0, stream>>>(wbases, wbT_hi, wbT_lo);
    k_setup_w1t<<<dim3(32), dim3(256), 0, stream>>>(W1, w1t_hi, w1t_lo);
    k_fc0<<<dim3(512, B_SZ), dim3(256), 0, stream>>>(x, W0, b0, h_hi, h_lo);

    for (int lay = 0; lay < N_LAY; ++lay) {
        int last = (lay == N_LAY - 1);
        k_zero<<<dim3(2048), dim3(256), 0, stream>>>(ybuf, 524288);  // ybuf + xh
        k_spectral_mfma<<<dim3(B_SZ, 16), dim3(256), 0, stream>>>(
            h_hi, h_lo, wbT_hi, wbT_lo, xh);
        k_hmix<<<dim3(B_SZ, JM), dim3(256), 0, stream>>>(xh, Hbuf, Wsp, ybuf, lay);
        k_build_A<<<dim3(B_SZ), dim3(256), 0, stream>>>(ybuf, Wconv, Abuf_hi, Abuf_lo, lay);
        dim3 g(B_SZ, 128), blk(256);
        if (full) {
            if (last)
                k_inv_conv_mfma<true, true><<<g, blk, 0, stream>>>(
                    Abuf_hi, Abuf_lo, bases_hi, bases_lo, h_hi, h_lo, bconv, lay,
                    w1t_hi, w1t_lo, b1, W2, b2, out);
            else
                k_inv_conv_mfma<true, false><<<g, blk, 0, stream>>>(
                    Abuf_hi, Abuf_lo, bases_hi, bases_lo, h_hi, h_lo, bconv, lay,
                    w1t_hi, w1t_lo, b1, W2, b2, out);
        } else {
            if (last)
                k_inv_conv_mfma<false, true><<<g, blk, 0, stream>>>(
                    Abuf_hi, Abuf_lo, bases_hi, bases_hi, h_hi, h_lo, bconv, lay,
                    w1t_hi, w1t_lo, b1, W2, b2, out);
            else
                k_inv_conv_mfma<false, false><<<g, blk, 0, stream>>>(
                    Abuf_hi, Abuf_lo, bases_hi, bases_hi, h_hi, h_lo, bconv, lay,
                    w1t_hi, w1t_lo, b1, W2, b2, out);
        }
    }
}

// Round 8
// 749.141 us; speedup vs baseline: 1.2868x; 1.1195x over previous
//
#include <hip/hip_runtime.h>
#include <hip/hip_bf16.h>
#include <math.h>

#define B_SZ   32
#define NXX    16384
#define IN_DIM 3
#define DIM    64
#define JM     16
#define MODE   128
#define RANKK  4
#define FC_DIM 128
#define N_LAY  3

typedef __attribute__((ext_vector_type(8))) short bf16x8;
typedef __attribute__((ext_vector_type(4))) float f32x4;
typedef unsigned short u16;

__device__ __forceinline__ float gelu_exact(float v) {
    return 0.5f * v * (1.0f + erff(v * 0.70710678118654752f));
}
__device__ __forceinline__ void split_bf16(float v, u16& h, u16& l) {
    __hip_bfloat16 bh = __float2bfloat16(v);
    float fh = __bfloat162float(bh);
    __hip_bfloat16 bl = __float2bfloat16(v - fh);
    h = *(u16*)&bh;
    l = *(u16*)&bl;
}
__device__ __forceinline__ u16 to_bf16(float v) {
    __hip_bfloat16 b = __float2bfloat16(v);
    return *(u16*)&b;
}

// ---------------------------------------------------------------------------
__global__ __launch_bounds__(256) void k_zero(float* __restrict__ p, int n) {
    int i = blockIdx.x * 256 + threadIdx.x;
    if (i < n) p[i] = 0.f;
}

// H[j,k,l] = D_out[j,k]*D_in[j,l]*product[k,l] + sum_r A[j,r,k]*Bm[j,r,l]
__global__ __launch_bounds__(256) void k_build_H(
        const float* __restrict__ Dout, const float* __restrict__ Din,
        const float* __restrict__ product, const float* __restrict__ A,
        const float* __restrict__ Bm, float* __restrict__ H) {
    int idx = blockIdx.x * 256 + threadIdx.x;
    int j = idx >> 14;
    int k = (idx >> 7) & 127;
    int l = idx & 127;
    float v = Dout[j * MODE + k] * Din[j * MODE + l] * product[k * MODE + l];
#pragma unroll
    for (int r = 0; r < RANKK; ++r)
        v += A[(j * RANKK + r) * MODE + k] * Bm[(j * RANKK + r) * MODE + l];
    H[idx] = v;
}

// bases (fp32 [x][k]) -> FRAG-MAJOR hi/lo planes:
//   Bf[(k>>3)*131072 + x*8 + (k&7)]   grid 8192 x 256.
__global__ __launch_bounds__(256) void k_setup_bases(
        const float* __restrict__ bases, u16* __restrict__ bh, u16* __restrict__ bl) {
    int idx = blockIdx.x * 256 + threadIdx.x;
    int x = idx >> 7, k = idx & 127;
    u16 h, l;
    split_bf16(bases[idx], h, l);
    size_t off = (size_t)(k >> 3) * 131072 + (size_t)x * 8 + (k & 7);
    bh[off] = h;
    bl[off] = l;
}

// wbT[l][x] = wbases[x][l], split hi/lo.  grid (512, 4) x 256, LDS-tiled.
__global__ __launch_bounds__(256) void k_setup_wbT(
        const float* __restrict__ wb, u16* __restrict__ Th, u16* __restrict__ Tl) {
    __shared__ float tile[32][33];
    int bx = blockIdx.x, bl = blockIdx.y;
    int t = threadIdx.x;
    int i = t >> 5, jj = t & 31;
#pragma unroll
    for (int r = 0; r < 4; ++r)
        tile[i + r * 8][jj] = wb[(size_t)(bx * 32 + i + r * 8) * MODE + bl * 32 + jj];
    __syncthreads();
#pragma unroll
    for (int r = 0; r < 4; ++r) {
        int l = bl * 32 + i + r * 8;
        int x = bx * 32 + jj;
        u16 h, lo;
        split_bf16(tile[jj][i + r * 8], h, lo);
        Th[(size_t)l * NXX + x] = h;
        Tl[(size_t)l * NXX + x] = lo;
    }
}

// W1T[f*64+c] = W1[c*128+f] hi/lo.  grid 32 x 256
__global__ __launch_bounds__(256) void k_setup_w1t(
        const float* __restrict__ W1, u16* __restrict__ wh, u16* __restrict__ wl) {
    int i = blockIdx.x * 256 + threadIdx.x;
    int f = i >> 6, c = i & 63;
    u16 h, l;
    split_bf16(W1[c * FC_DIM + f], h, l);
    wh[i] = h; wl[i] = l;
}

// fc0: h[b,x,c] (single bf16 plane), coalesced ushort8 stores.
// grid (512, 32) x 256.
__global__ __launch_bounds__(256) void k_fc0(
        const float* __restrict__ x, const float* __restrict__ W0,
        const float* __restrict__ b0, u16* __restrict__ hh) {
    __shared__ float w0s[IN_DIM * DIM + DIM];
    int t = threadIdx.x;
    if (t < IN_DIM * DIM) w0s[t] = W0[t];
    if (t < DIM) w0s[IN_DIM * DIM + t] = b0[t];
    __syncthreads();
    int b = blockIdx.y;
    int xi = blockIdx.x * 32 + (t >> 3);
    int c8 = (t & 7) * 8;
    const float* xp = x + ((size_t)b * NXX + xi) * IN_DIM;
    float x0 = xp[0], x1 = xp[1], x2 = xp[2];
    u16 rh[8];
#pragma unroll
    for (int i = 0; i < 8; ++i) {
        int c = c8 + i;
        float v = x0 * w0s[c] + x1 * w0s[DIM + c] + x2 * w0s[2 * DIM + c]
                + w0s[3 * DIM + c];
        rh[i] = to_bf16(v);
    }
    size_t o = ((size_t)(b << 14) + xi) * 64 + c8;
    *(ushort4*)(hh + o)     = make_ushort4(rh[0], rh[1], rh[2], rh[3]);
    *(ushort4*)(hh + o + 4) = make_ushort4(rh[4], rh[5], rh[6], rh[7]);
}

// ---------------------------------------------------------------------------
// Spectral via MFMA: xh[b][c][l] += sum_x h[b][x][c] * wbases[x][l]
// h single bf16 plane; wbases hi/lo.  Rotation-swizzled LDS transpose.
// grid (32 b, 16 ks) x 256 (4 waves; wave = 16c x 32l).
#define SPAD 72
__global__ __launch_bounds__(256) void k_spectral_mfma(
        const u16* __restrict__ Hh,
        const u16* __restrict__ Wh, const u16* __restrict__ Wl,
        float* __restrict__ xh) {
    __shared__ u16 Ash[64 * SPAD];
    int t = threadIdx.x;
    int wave = t >> 6, lane = t & 63, quad = lane >> 4, l16 = lane & 15;
    int b = blockIdx.x;
    int x0 = blockIdx.y * 1024;
    int cq = (t & 15) * 4;
    int xq = (t >> 4) * 4;
    int colw = (xq + ((t & 7) << 3)) & 63;
    const u16* srch = Hh + ((size_t)(b << 14) + x0 + xq) * 64 + cq;
    int l0 = wave * 32;
    const u16* w0h = Wh + (size_t)(l0 + l16) * NXX + x0;
    const u16* w1h = Wh + (size_t)(l0 + 16 + l16) * NXX + x0;
    const u16* w0l = Wl + (size_t)(l0 + l16) * NXX + x0;
    const u16* w1l = Wl + (size_t)(l0 + 16 + l16) * NXX + x0;
    f32x4 acc[4][2] = {};
    for (int kt = 0; kt < 1024; kt += 64) {
        __syncthreads();
        {
            const u16* s = srch + (size_t)kt * 64;
            ushort4 r0 = *(const ushort4*)(s);
            ushort4 r1 = *(const ushort4*)(s + 64);
            ushort4 r2 = *(const ushort4*)(s + 128);
            ushort4 r3 = *(const ushort4*)(s + 192);
            *(ushort4*)&Ash[(cq + 0) * SPAD + colw] = make_ushort4(r0.x, r1.x, r2.x, r3.x);
            *(ushort4*)&Ash[(cq + 1) * SPAD + colw] = make_ushort4(r0.y, r1.y, r2.y, r3.y);
            *(ushort4*)&Ash[(cq + 2) * SPAD + colw] = make_ushort4(r0.z, r1.z, r2.z, r3.z);
            *(ushort4*)&Ash[(cq + 3) * SPAD + colw] = make_ushort4(r0.w, r1.w, r2.w, r3.w);
        }
        __syncthreads();
#pragma unroll
        for (int k0 = 0; k0 < 64; k0 += 32) {
            bf16x8 afh[4];
#pragma unroll
            for (int ct = 0; ct < 4; ++ct) {
                int rr = ct * 16 + l16;
                int ro = rr * SPAD + (((k0 + quad * 8) + (((rr >> 2) & 7) << 3)) & 63);
                afh[ct] = *(const bf16x8*)&Ash[ro];
            }
            int go = kt + k0 + quad * 8;
            bf16x8 b0h = *(const bf16x8*)(w0h + go);
            bf16x8 b0l = *(const bf16x8*)(w0l + go);
            bf16x8 b1h = *(const bf16x8*)(w1h + go);
            bf16x8 b1l = *(const bf16x8*)(w1l + go);
#pragma unroll
            for (int ct = 0; ct < 4; ++ct) {
                acc[ct][0] = __builtin_amdgcn_mfma_f32_16x16x32_bf16(afh[ct], b0l, acc[ct][0], 0, 0, 0);
                acc[ct][0] = __builtin_amdgcn_mfma_f32_16x16x32_bf16(afh[ct], b0h, acc[ct][0], 0, 0, 0);
                acc[ct][1] = __builtin_amdgcn_mfma_f32_16x16x32_bf16(afh[ct], b1l, acc[ct][1], 0, 0, 0);
                acc[ct][1] = __builtin_amdgcn_mfma_f32_16x16x32_bf16(afh[ct], b1h, acc[ct][1], 0, 0, 0);
            }
        }
    }
    float* xb = xh + (size_t)(b << 6) * 128;
#pragma unroll
    for (int ct = 0; ct < 4; ++ct)
#pragma unroll
        for (int lt = 0; lt < 2; ++lt)
#pragma unroll
            for (int r = 0; r < 4; ++r)
                atomicAdd(xb + (size_t)(ct * 16 + quad * 4 + r) * 128 + l0 + lt * 16 + l16,
                          acc[ct][lt][r]);
}

// ---------------------------------------------------------------------------
// Fused H-mix + channel contraction.  grid (32, 16) x 256
__global__ __launch_bounds__(256) void k_hmix(
        const float* __restrict__ xh, const float* __restrict__ H,
        const float* __restrict__ Wsp, float* __restrict__ y, int lay) {
    __shared__ float xs[DIM][132];
    __shared__ float Ts[DIM][MODE];
    __shared__ float Ws[DIM][DIM];
    int t = threadIdx.x;
    int b = blockIdx.x;
    int j = blockIdx.y;
    const float* xb = xh + (size_t)b * DIM * MODE;
    for (int idx = t; idx < DIM * MODE; idx += 256)
        xs[idx >> 7][idx & 127] = xb[idx];
    const float* Wl = Wsp + (size_t)lay * DIM * DIM * JM + j;
    for (int idx = t; idx < DIM * DIM; idx += 256)
        Ws[idx >> 6][idx & 63] = Wl[(size_t)idx * JM];
    __syncthreads();
    {
        int k4 = (t & 31) * 4;
        int i0 = (t >> 5) * 8;
        float acc[8][4] = {};
        const float* Hbase = H + ((size_t)j * MODE + k4) * MODE;
        for (int l = 0; l < MODE; l += 4) {
            float4 hv0 = *(const float4*)(Hbase + 0 * MODE + l);
            float4 hv1 = *(const float4*)(Hbase + 1 * MODE + l);
            float4 hv2 = *(const float4*)(Hbase + 2 * MODE + l);
            float4 hv3 = *(const float4*)(Hbase + 3 * MODE + l);
#pragma unroll
            for (int ii = 0; ii < 8; ++ii) {
                float4 xv = *(const float4*)&xs[i0 + ii][l];
                acc[ii][0] += hv0.x * xv.x + hv0.y * xv.y + hv0.z * xv.z + hv0.w * xv.w;
                acc[ii][1] += hv1.x * xv.x + hv1.y * xv.y + hv1.z * xv.z + hv1.w * xv.w;
                acc[ii][2] += hv2.x * xv.x + hv2.y * xv.y + hv2.z * xv.z + hv2.w * xv.w;
                acc[ii][3] += hv3.x * xv.x + hv3.y * xv.y + hv3.z * xv.z + hv3.w * xv.w;
            }
        }
#pragma unroll
        for (int ii = 0; ii < 8; ++ii)
            *(float4*)&Ts[i0 + ii][k4] = make_float4(acc[ii][0], acc[ii][1], acc[ii][2], acc[ii][3]);
    }
    __syncthreads();
    {
        int k = t & 127;
        int o0 = (t >> 7) * 32;
        float acc2[32] = {};
        for (int i = 0; i < DIM; ++i) {
            float tv = Ts[i][k];
            const float* wr = &Ws[i][o0];
#pragma unroll
            for (int o4 = 0; o4 < 32; o4 += 4) {
                float4 wv = *(const float4*)(wr + o4);
                acc2[o4 + 0] += wv.x * tv;
                acc2[o4 + 1] += wv.y * tv;
                acc2[o4 + 2] += wv.z * tv;
                acc2[o4 + 3] += wv.w * tv;
            }
        }
        float* yp = y + ((size_t)b * DIM + o0) * MODE + k;
#pragma unroll
        for (int o = 0; o < 32; ++o)
            atomicAdd(yp + (size_t)o * MODE, acc2[o]);
    }
}

// A buffer in FRAG-MAJOR layout (y|Wconv hi/lo).  grid (32) x 256
__global__ __launch_bounds__(256) void k_build_A(
        const float* __restrict__ y, const float* __restrict__ Wconv,
        u16* __restrict__ Ah, u16* __restrict__ Al, int lay) {
    int b = blockIdx.x;
    for (int idx = threadIdx.x; idx < 12288; idx += 256) {
        int i = idx & 7, l16 = (idx >> 3) & 15, quad = (idx >> 7) & 3,
            ot = (idx >> 9) & 3, ks = idx >> 11;
        int o = ot * 16 + l16;
        int k = ks * 32 + quad * 8 + i;
        float v = (k < 128) ? y[((size_t)b * DIM + o) * MODE + k]
                            : Wconv[(size_t)lay * DIM * DIM + o * DIM + (k - 128)];
        u16 h, l;
        split_bf16(v, h, l);
        size_t off = (size_t)b * 12288 + idx;
        Ah[off] = h; Al[off] = l;
    }
}

// ---------------------------------------------------------------------------
// inv_conv v5: h' = act(A(64x192) @ B(192 x 128x) + bconv), in-place on h
// (single bf16 plane).  ks<4: bases hi/lo B (3 MFMA); ks>=4: h bf16 B (2 MFMA).
// DO_MLP (compile-time): lay2 computes final MLP from LDS tile, skips
// writeback.  grid (32 b, 128 xt) x 256 (4 waves; wave = 64o x 32x).
#define CPAD 72
template <bool DO_MLP>
__global__ __launch_bounds__(256, DO_MLP ? 2 : 4) void k_inv_conv_mfma(
        const u16* __restrict__ Afh, const u16* __restrict__ Afl,
        const u16* __restrict__ Bfh, const u16* __restrict__ Bfl,
        u16* __restrict__ Hh,
        const float* __restrict__ bconv, int lay,
        const u16* __restrict__ W1h, const u16* __restrict__ W1l,
        const float* __restrict__ b1, const float* __restrict__ W2,
        const float* __restrict__ b2, float* __restrict__ out) {
    __shared__ u16 hsh[128 * CPAD];
    int t = threadIdx.x;
    int wave = t >> 6, lane = t & 63, quad = lane >> 4, l16 = lane & 15;
    int b = blockIdx.x;
    int x0 = blockIdx.y * 128;
#pragma unroll
    for (int it = 0; it < 4; ++it) {
        int idx = it * 256 + t;
        int row = idx >> 3, c8 = (idx & 7) * 8;
        size_t src = ((size_t)(b << 14) + x0 + row) * 64 + c8;
        *(bf16x8*)&hsh[row * CPAD + c8] = *(const bf16x8*)(Hh + src);
    }
    __syncthreads();

    int xw = wave * 32;
    const u16* afb_h = Afh + (size_t)b * 12288;
    const u16* afb_l = Afl + (size_t)b * 12288;
    f32x4 acc[4][2] = {};
#pragma unroll
    for (int ks = 0; ks < 6; ++ks) {
        bf16x8 afh[4], afl[4], bfh[2], bfl[2];
#pragma unroll
        for (int ot = 0; ot < 4; ++ot) {
            size_t ao = (size_t)(((ks * 4 + ot) * 4 + quad) * 16 + l16) * 8;
            afh[ot] = *(const bf16x8*)(afb_h + ao);
            afl[ot] = *(const bf16x8*)(afb_l + ao);
        }
        bool isbase = ks < 4;
#pragma unroll
        for (int x2 = 0; x2 < 2; ++x2) {
            int xl = xw + x2 * 16 + l16;
            if (isbase) {
                size_t bo = (size_t)((ks * 4 + quad) * 16384 + x0 + xl) * 8;
                bfh[x2] = *(const bf16x8*)(Bfh + bo);
                bfl[x2] = *(const bf16x8*)(Bfl + bo);
            } else {
                int ko = (ks - 4) * 32 + quad * 8;
                bfh[x2] = *(const bf16x8*)&hsh[xl * CPAD + ko];
            }
        }
#pragma unroll
        for (int ot = 0; ot < 4; ++ot)
#pragma unroll
            for (int x2 = 0; x2 < 2; ++x2) {
                if (isbase)
                    acc[ot][x2] = __builtin_amdgcn_mfma_f32_16x16x32_bf16(afh[ot], bfl[x2], acc[ot][x2], 0, 0, 0);
                acc[ot][x2] = __builtin_amdgcn_mfma_f32_16x16x32_bf16(afl[ot], bfh[x2], acc[ot][x2], 0, 0, 0);
                acc[ot][x2] = __builtin_amdgcn_mfma_f32_16x16x32_bf16(afh[ot], bfh[x2], acc[ot][x2], 0, 0, 0);
            }
    }
    __syncthreads();   // all LDS h reads done -> reuse hsh for C staging

#pragma unroll
    for (int ot = 0; ot < 4; ++ot) {
        float4 bc = *(const float4*)(bconv + lay * DIM + ot * 16 + quad * 4);
#pragma unroll
        for (int x2 = 0; x2 < 2; ++x2) {
            int xl = xw + x2 * 16 + l16;
            float vr[4] = {acc[ot][x2][0] + bc.x, acc[ot][x2][1] + bc.y,
                           acc[ot][x2][2] + bc.z, acc[ot][x2][3] + bc.w};
            if (!DO_MLP) {   // gelu between layers; final layer has no act
#pragma unroll
                for (int r = 0; r < 4; ++r) vr[r] = gelu_exact(vr[r]);
            }
            ushort4 uh;
            uh.x = to_bf16(vr[0]); uh.y = to_bf16(vr[1]);
            uh.z = to_bf16(vr[2]); uh.w = to_bf16(vr[3]);
            *(ushort4*)&hsh[xl * CPAD + ot * 16 + quad * 4] = uh;
        }
    }
    __syncthreads();

    if (!DO_MLP) {
#pragma unroll
        for (int it = 0; it < 4; ++it) {
            int idx = it * 256 + t;
            int row = idx >> 3, c8 = (idx & 7) * 8;
            size_t dst = ((size_t)(b << 14) + x0 + row) * 64 + c8;
            *(bf16x8*)(Hh + dst) = *(const bf16x8*)&hsh[row * CPAD + c8];
        }
        return;
    }

    // ---- fused final MLP (lay 2 only): out = gelu(h'@W1+b1)@W2 + b2 ----
#pragma unroll
    for (int x2 = 0; x2 < 2; ++x2) {
        bf16x8 ah[2];
#pragma unroll
        for (int ks = 0; ks < 2; ++ks) {
            int ro = (xw + x2 * 16 + l16) * CPAD + ks * 32 + quad * 8;
            ah[ks] = *(const bf16x8*)&hsh[ro];
        }
        float vo[4] = {0.f, 0.f, 0.f, 0.f};
#pragma unroll
        for (int ft = 0; ft < 8; ++ft) {
            f32x4 a2 = {};
#pragma unroll
            for (int ks = 0; ks < 2; ++ks) {
                size_t o = (size_t)(ft * 16 + l16) * 64 + ks * 32 + quad * 8;
                bf16x8 bh = *(const bf16x8*)(W1h + o);
                bf16x8 bl = *(const bf16x8*)(W1l + o);
                a2 = __builtin_amdgcn_mfma_f32_16x16x32_bf16(ah[ks], bl, a2, 0, 0, 0);
                a2 = __builtin_amdgcn_mfma_f32_16x16x32_bf16(ah[ks], bh, a2, 0, 0, 0);
            }
            float bb = b1[ft * 16 + l16];
            float w2 = W2[ft * 16 + l16];
#pragma unroll
            for (int r = 0; r < 4; ++r)
                vo[r] += gelu_exact(a2[r] + bb) * w2;
        }
#pragma unroll
        for (int r = 0; r < 4; ++r) {
            float v = vo[r];
            v += __shfl_xor(v, 1);
            v += __shfl_xor(v, 2);
            v += __shfl_xor(v, 4);
            v += __shfl_xor(v, 8);
            vo[r] = v;
        }
        if (l16 == 0) {
            float bb2 = b2[0];
            float4 o4 = make_float4(vo[0] + bb2, vo[1] + bb2, vo[2] + bb2, vo[3] + bb2);
            *(float4*)(out + (size_t)b * NXX + x0 + xw + x2 * 16 + quad * 4) = o4;
        }
    }
}

// ---------------------------------------------------------------------------
extern "C" void kernel_launch(void* const* d_in, const int* in_sizes, int n_in,
                              void* d_out, int out_size, void* d_ws, size_t ws_size,
                              hipStream_t stream) {
    const float* x      = (const float*)d_in[0];
    const float* bases  = (const float*)d_in[1];
    const float* wbases = (const float*)d_in[2];
    const float* product= (const float*)d_in[3];
    const float* Dout   = (const float*)d_in[4];
    const float* Din    = (const float*)d_in[5];
    const float* A      = (const float*)d_in[6];
    const float* Bm     = (const float*)d_in[7];
    const float* Wsp    = (const float*)d_in[8];
    const float* Wconv  = (const float*)d_in[9];
    const float* bconv  = (const float*)d_in[10];
    const float* W0     = (const float*)d_in[11];
    const float* b0     = (const float*)d_in[12];
    const float* W1     = (const float*)d_in[13];
    const float* b1     = (const float*)d_in[14];
    const float* W2     = (const float*)d_in[15];
    const float* b2     = (const float*)d_in[16];
    float* out = (float*)d_out;

    const size_t need = 88637440;   // single-plane h layout
    if (ws_size < need) {
        k_zero<<<dim3((out_size + 255) / 256), dim3(256), 0, stream>>>(out, out_size);
        return;
    }

    char* W = (char*)d_ws;
    size_t off = 0;
    auto alloc = [&](size_t bytes) { void* p = W + off; off += bytes; return p; };
    float* Hbuf     = (float*)alloc(1048576);
    u16*   bases_hi = (u16*)alloc(4194304);
    u16*   bases_lo = (u16*)alloc(4194304);
    u16*   wbT_hi   = (u16*)alloc(4194304);
    u16*   wbT_lo   = (u16*)alloc(4194304);
    u16*   Abuf_hi  = (u16*)alloc(786432);
    u16*   Abuf_lo  = (u16*)alloc(786432);
    float* ybuf     = (float*)alloc(1048576);
    float* xh       = (float*)alloc(1048576);   // must follow ybuf (joint zeroing)
    u16*   h_hi     = (u16*)alloc(67108864);
    u16*   w1t_hi   = (u16*)alloc(16384);
    u16*   w1t_lo   = (u16*)alloc(16384);

    k_build_H<<<dim3(1024), dim3(256), 0, stream>>>(Dout, Din, product, A, Bm, Hbuf);
    k_setup_bases<<<dim3(8192), dim3(256), 0, stream>>>(bases, bases_hi, bases_lo);
    k_setup_wbT<<<dim3(512, 4), dim3(256), 0, stream>>>(wbases, wbT_hi, wbT_lo);
    k_setup_w1t<<<dim3(32), dim3(256), 0, stream>>>(W1, w1t_hi, w1t_lo);
    k_fc0<<<dim3(512, B_SZ), dim3(256), 0, stream>>>(x, W0, b0, h_hi);

    for (int lay = 0; lay < N_LAY; ++lay) {
        int last = (lay == N_LAY - 1);
        k_zero<<<dim3(2048), dim3(256), 0, stream>>>(ybuf, 524288);  // ybuf + xh
        k_spectral_mfma<<<dim3(B_SZ, 16), dim3(256), 0, stream>>>(
            h_hi, wbT_hi, wbT_lo, xh);
        k_hmix<<<dim3(B_SZ, JM), dim3(256), 0, stream>>>(xh, Hbuf, Wsp, ybuf, lay);
        k_build_A<<<dim3(B_SZ), dim3(256), 0, stream>>>(ybuf, Wconv, Abuf_hi, Abuf_lo, lay);
        dim3 g(B_SZ, 128), blk(256);
        if (last)
            k_inv_conv_mfma<true><<<g, blk, 0, stream>>>(
                Abuf_hi, Abuf_lo, bases_hi, bases_lo, h_hi, bconv, lay,
                w1t_hi, w1t_lo, b1, W2, b2, out);
        else
            k_inv_conv_mfma<false><<<g, blk, 0, stream>>>(
                Abuf_hi, Abuf_lo, bases_hi, bases_lo, h_hi, bconv, lay,
                w1t_hi, w1t_lo, b1, W2, b2, out);
    }
}

// Round 9
// 688.662 us; speedup vs baseline: 1.3998x; 1.0878x over previous
//
#include <hip/hip_runtime.h>
#include <hip/hip_bf16.h>
#include <math.h>

#define B_SZ   32
#define NXX    16384
#define IN_DIM 3
#define DIM    64
#define JM     16
#define MODE   128
#define RANKK  4
#define FC_DIM 128
#define N_LAY  3

typedef __attribute__((ext_vector_type(8))) short bf16x8;
typedef __attribute__((ext_vector_type(4))) float f32x4;
typedef unsigned short u16;

__device__ __forceinline__ float gelu_exact(float v) {
    return 0.5f * v * (1.0f + erff(v * 0.70710678118654752f));
}
__device__ __forceinline__ void split_bf16(float v, u16& h, u16& l) {
    __hip_bfloat16 bh = __float2bfloat16(v);
    float fh = __bfloat162float(bh);
    __hip_bfloat16 bl = __float2bfloat16(v - fh);
    h = *(u16*)&bh;
    l = *(u16*)&bl;
}
__device__ __forceinline__ u16 to_bf16(float v) {
    __hip_bfloat16 b = __float2bfloat16(v);
    return *(u16*)&b;
}

// ---------------------------------------------------------------------------
__global__ __launch_bounds__(256) void k_zero(float* __restrict__ p, int n) {
    int i = blockIdx.x * 256 + threadIdx.x;
    if (i < n) p[i] = 0.f;
}

// H[j,k,l] = D_out[j,k]*D_in[j,l]*product[k,l] + sum_r A[j,r,k]*Bm[j,r,l]
__global__ __launch_bounds__(256) void k_build_H(
        const float* __restrict__ Dout, const float* __restrict__ Din,
        const float* __restrict__ product, const float* __restrict__ A,
        const float* __restrict__ Bm, float* __restrict__ H) {
    int idx = blockIdx.x * 256 + threadIdx.x;
    int j = idx >> 14;
    int k = (idx >> 7) & 127;
    int l = idx & 127;
    float v = Dout[j * MODE + k] * Din[j * MODE + l] * product[k * MODE + l];
#pragma unroll
    for (int r = 0; r < RANKK; ++r)
        v += A[(j * RANKK + r) * MODE + k] * Bm[(j * RANKK + r) * MODE + l];
    H[idx] = v;
}

// bases (fp32 [x][k]) -> FRAG-MAJOR single bf16 plane:
//   Bf[(k>>3)*131072 + x*8 + (k&7)]   grid 8192 x 256.
__global__ __launch_bounds__(256) void k_setup_bases(
        const float* __restrict__ bases, u16* __restrict__ bh) {
    int idx = blockIdx.x * 256 + threadIdx.x;
    int x = idx >> 7, k = idx & 127;
    size_t off = (size_t)(k >> 3) * 131072 + (size_t)x * 8 + (k & 7);
    bh[off] = to_bf16(bases[idx]);
}

// wbT[l][x] = wbases[x][l], split hi/lo (spectral keeps full precision).
// grid (512, 4) x 256, LDS-tiled.
__global__ __launch_bounds__(256) void k_setup_wbT(
        const float* __restrict__ wb, u16* __restrict__ Th, u16* __restrict__ Tl) {
    __shared__ float tile[32][33];
    int bx = blockIdx.x, bl = blockIdx.y;
    int t = threadIdx.x;
    int i = t >> 5, jj = t & 31;
#pragma unroll
    for (int r = 0; r < 4; ++r)
        tile[i + r * 8][jj] = wb[(size_t)(bx * 32 + i + r * 8) * MODE + bl * 32 + jj];
    __syncthreads();
#pragma unroll
    for (int r = 0; r < 4; ++r) {
        int l = bl * 32 + i + r * 8;
        int x = bx * 32 + jj;
        u16 h, lo;
        split_bf16(tile[jj][i + r * 8], h, lo);
        Th[(size_t)l * NXX + x] = h;
        Tl[(size_t)l * NXX + x] = lo;
    }
}

// W1T[f*64+c] = W1[c*128+f] single bf16 plane.  grid 32 x 256
__global__ __launch_bounds__(256) void k_setup_w1t(
        const float* __restrict__ W1, u16* __restrict__ wh) {
    int i = blockIdx.x * 256 + threadIdx.x;
    int f = i >> 6, c = i & 63;
    wh[i] = to_bf16(W1[c * FC_DIM + f]);
}

// fc0: h[b,x,c] (single bf16 plane), coalesced ushort8 stores.
// grid (512, 32) x 256.
__global__ __launch_bounds__(256) void k_fc0(
        const float* __restrict__ x, const float* __restrict__ W0,
        const float* __restrict__ b0, u16* __restrict__ hh) {
    __shared__ float w0s[IN_DIM * DIM + DIM];
    int t = threadIdx.x;
    if (t < IN_DIM * DIM) w0s[t] = W0[t];
    if (t < DIM) w0s[IN_DIM * DIM + t] = b0[t];
    __syncthreads();
    int b = blockIdx.y;
    int xi = blockIdx.x * 32 + (t >> 3);
    int c8 = (t & 7) * 8;
    const float* xp = x + ((size_t)b * NXX + xi) * IN_DIM;
    float x0 = xp[0], x1 = xp[1], x2 = xp[2];
    u16 rh[8];
#pragma unroll
    for (int i = 0; i < 8; ++i) {
        int c = c8 + i;
        float v = x0 * w0s[c] + x1 * w0s[DIM + c] + x2 * w0s[2 * DIM + c]
                + w0s[3 * DIM + c];
        rh[i] = to_bf16(v);
    }
    size_t o = ((size_t)(b << 14) + xi) * 64 + c8;
    *(ushort4*)(hh + o)     = make_ushort4(rh[0], rh[1], rh[2], rh[3]);
    *(ushort4*)(hh + o + 4) = make_ushort4(rh[4], rh[5], rh[6], rh[7]);
}

// ---------------------------------------------------------------------------
// Spectral via MFMA: xh[b][c][l] += sum_x h[b][x][c] * wbases[x][l]
// h single bf16 plane; wbases hi/lo.  Rotation-swizzled LDS transpose.
// grid (32 b, 16 ks) x 256 (4 waves; wave = 16c x 32l).
#define SPAD 72
__global__ __launch_bounds__(256) void k_spectral_mfma(
        const u16* __restrict__ Hh,
        const u16* __restrict__ Wh, const u16* __restrict__ Wl,
        float* __restrict__ xh) {
    __shared__ u16 Ash[64 * SPAD];
    int t = threadIdx.x;
    int wave = t >> 6, lane = t & 63, quad = lane >> 4, l16 = lane & 15;
    int b = blockIdx.x;
    int x0 = blockIdx.y * 1024;
    int cq = (t & 15) * 4;
    int xq = (t >> 4) * 4;
    int colw = (xq + ((t & 7) << 3)) & 63;
    const u16* srch = Hh + ((size_t)(b << 14) + x0 + xq) * 64 + cq;
    int l0 = wave * 32;
    const u16* w0h = Wh + (size_t)(l0 + l16) * NXX + x0;
    const u16* w1h = Wh + (size_t)(l0 + 16 + l16) * NXX + x0;
    const u16* w0l = Wl + (size_t)(l0 + l16) * NXX + x0;
    const u16* w1l = Wl + (size_t)(l0 + 16 + l16) * NXX + x0;
    f32x4 acc[4][2] = {};
    for (int kt = 0; kt < 1024; kt += 64) {
        __syncthreads();
        {
            const u16* s = srch + (size_t)kt * 64;
            ushort4 r0 = *(const ushort4*)(s);
            ushort4 r1 = *(const ushort4*)(s + 64);
            ushort4 r2 = *(const ushort4*)(s + 128);
            ushort4 r3 = *(const ushort4*)(s + 192);
            *(ushort4*)&Ash[(cq + 0) * SPAD + colw] = make_ushort4(r0.x, r1.x, r2.x, r3.x);
            *(ushort4*)&Ash[(cq + 1) * SPAD + colw] = make_ushort4(r0.y, r1.y, r2.y, r3.y);
            *(ushort4*)&Ash[(cq + 2) * SPAD + colw] = make_ushort4(r0.z, r1.z, r2.z, r3.z);
            *(ushort4*)&Ash[(cq + 3) * SPAD + colw] = make_ushort4(r0.w, r1.w, r2.w, r3.w);
        }
        __syncthreads();
#pragma unroll
        for (int k0 = 0; k0 < 64; k0 += 32) {
            bf16x8 afh[4];
#pragma unroll
            for (int ct = 0; ct < 4; ++ct) {
                int rr = ct * 16 + l16;
                int ro = rr * SPAD + (((k0 + quad * 8) + (((rr >> 2) & 7) << 3)) & 63);
                afh[ct] = *(const bf16x8*)&Ash[ro];
            }
            int go = kt + k0 + quad * 8;
            bf16x8 b0h = *(const bf16x8*)(w0h + go);
            bf16x8 b0l = *(const bf16x8*)(w0l + go);
            bf16x8 b1h = *(const bf16x8*)(w1h + go);
            bf16x8 b1l = *(const bf16x8*)(w1l + go);
#pragma unroll
            for (int ct = 0; ct < 4; ++ct) {
                acc[ct][0] = __builtin_amdgcn_mfma_f32_16x16x32_bf16(afh[ct], b0l, acc[ct][0], 0, 0, 0);
                acc[ct][0] = __builtin_amdgcn_mfma_f32_16x16x32_bf16(afh[ct], b0h, acc[ct][0], 0, 0, 0);
                acc[ct][1] = __builtin_amdgcn_mfma_f32_16x16x32_bf16(afh[ct], b1l, acc[ct][1], 0, 0, 0);
                acc[ct][1] = __builtin_amdgcn_mfma_f32_16x16x32_bf16(afh[ct], b1h, acc[ct][1], 0, 0, 0);
            }
        }
    }
    float* xb = xh + (size_t)(b << 6) * 128;
#pragma unroll
    for (int ct = 0; ct < 4; ++ct)
#pragma unroll
        for (int lt = 0; lt < 2; ++lt)
#pragma unroll
            for (int r = 0; r < 4; ++r)
                atomicAdd(xb + (size_t)(ct * 16 + quad * 4 + r) * 128 + l0 + lt * 16 + l16,
                          acc[ct][lt][r]);
}

// ---------------------------------------------------------------------------
// Fused H-mix + channel contraction.  grid (32, 16) x 256
__global__ __launch_bounds__(256) void k_hmix(
        const float* __restrict__ xh, const float* __restrict__ H,
        const float* __restrict__ Wsp, float* __restrict__ y, int lay) {
    __shared__ float xs[DIM][132];
    __shared__ float Ts[DIM][MODE];
    __shared__ float Ws[DIM][DIM];
    int t = threadIdx.x;
    int b = blockIdx.x;
    int j = blockIdx.y;
    const float* xb = xh + (size_t)b * DIM * MODE;
    for (int idx = t; idx < DIM * MODE; idx += 256)
        xs[idx >> 7][idx & 127] = xb[idx];
    const float* Wl = Wsp + (size_t)lay * DIM * DIM * JM + j;
    for (int idx = t; idx < DIM * DIM; idx += 256)
        Ws[idx >> 6][idx & 63] = Wl[(size_t)idx * JM];
    __syncthreads();
    {
        int k4 = (t & 31) * 4;
        int i0 = (t >> 5) * 8;
        float acc[8][4] = {};
        const float* Hbase = H + ((size_t)j * MODE + k4) * MODE;
        for (int l = 0; l < MODE; l += 4) {
            float4 hv0 = *(const float4*)(Hbase + 0 * MODE + l);
            float4 hv1 = *(const float4*)(Hbase + 1 * MODE + l);
            float4 hv2 = *(const float4*)(Hbase + 2 * MODE + l);
            float4 hv3 = *(const float4*)(Hbase + 3 * MODE + l);
#pragma unroll
            for (int ii = 0; ii < 8; ++ii) {
                float4 xv = *(const float4*)&xs[i0 + ii][l];
                acc[ii][0] += hv0.x * xv.x + hv0.y * xv.y + hv0.z * xv.z + hv0.w * xv.w;
                acc[ii][1] += hv1.x * xv.x + hv1.y * xv.y + hv1.z * xv.z + hv1.w * xv.w;
                acc[ii][2] += hv2.x * xv.x + hv2.y * xv.y + hv2.z * xv.z + hv2.w * xv.w;
                acc[ii][3] += hv3.x * xv.x + hv3.y * xv.y + hv3.z * xv.z + hv3.w * xv.w;
            }
        }
#pragma unroll
        for (int ii = 0; ii < 8; ++ii)
            *(float4*)&Ts[i0 + ii][k4] = make_float4(acc[ii][0], acc[ii][1], acc[ii][2], acc[ii][3]);
    }
    __syncthreads();
    {
        int k = t & 127;
        int o0 = (t >> 7) * 32;
        float acc2[32] = {};
        for (int i = 0; i < DIM; ++i) {
            float tv = Ts[i][k];
            const float* wr = &Ws[i][o0];
#pragma unroll
            for (int o4 = 0; o4 < 32; o4 += 4) {
                float4 wv = *(const float4*)(wr + o4);
                acc2[o4 + 0] += wv.x * tv;
                acc2[o4 + 1] += wv.y * tv;
                acc2[o4 + 2] += wv.z * tv;
                acc2[o4 + 3] += wv.w * tv;
            }
        }
        float* yp = y + ((size_t)b * DIM + o0) * MODE + k;
#pragma unroll
        for (int o = 0; o < 32; ++o)
            atomicAdd(yp + (size_t)o * MODE, acc2[o]);
    }
}

// A buffer in FRAG-MAJOR layout (y|Wconv, single bf16 plane).  grid (32) x 256
__global__ __launch_bounds__(256) void k_build_A(
        const float* __restrict__ y, const float* __restrict__ Wconv,
        u16* __restrict__ Ah, int lay) {
    int b = blockIdx.x;
    for (int idx = threadIdx.x; idx < 12288; idx += 256) {
        int i = idx & 7, l16 = (idx >> 3) & 15, quad = (idx >> 7) & 3,
            ot = (idx >> 9) & 3, ks = idx >> 11;
        int o = ot * 16 + l16;
        int k = ks * 32 + quad * 8 + i;
        float v = (k < 128) ? y[((size_t)b * DIM + o) * MODE + k]
                            : Wconv[(size_t)lay * DIM * DIM + o * DIM + (k - 128)];
        Ah[(size_t)b * 12288 + idx] = to_bf16(v);
    }
}

// ---------------------------------------------------------------------------
// inv_conv v6: h' = act(A(64x192) @ B(192 x 128x) + bconv), in-place on h.
// ALL single bf16 plane (A, bases, h) -> 1 MFMA per frag pair, 48 MFMA/wave.
// DO_MLP (compile-time): lay2 computes final MLP from LDS tile (W1 bf16),
// skips writeback.  grid (32 b, 128 xt) x 256 (4 waves; wave = 64o x 32x).
#define CPAD 72
template <bool DO_MLP>
__global__ __launch_bounds__(256, 4) void k_inv_conv_mfma(
        const u16* __restrict__ Afh,
        const u16* __restrict__ Bfh,
        u16* __restrict__ Hh,
        const float* __restrict__ bconv, int lay,
        const u16* __restrict__ W1h,
        const float* __restrict__ b1, const float* __restrict__ W2,
        const float* __restrict__ b2, float* __restrict__ out) {
    __shared__ u16 hsh[128 * CPAD];
    int t = threadIdx.x;
    int wave = t >> 6, lane = t & 63, quad = lane >> 4, l16 = lane & 15;
    int b = blockIdx.x;
    int x0 = blockIdx.y * 128;
#pragma unroll
    for (int it = 0; it < 4; ++it) {
        int idx = it * 256 + t;
        int row = idx >> 3, c8 = (idx & 7) * 8;
        size_t src = ((size_t)(b << 14) + x0 + row) * 64 + c8;
        *(bf16x8*)&hsh[row * CPAD + c8] = *(const bf16x8*)(Hh + src);
    }
    __syncthreads();

    int xw = wave * 32;
    const u16* afb_h = Afh + (size_t)b * 12288;
    f32x4 acc[4][2] = {};
#pragma unroll
    for (int ks = 0; ks < 6; ++ks) {
        bf16x8 afh[4], bfh[2];
#pragma unroll
        for (int ot = 0; ot < 4; ++ot) {
            size_t ao = (size_t)(((ks * 4 + ot) * 4 + quad) * 16 + l16) * 8;
            afh[ot] = *(const bf16x8*)(afb_h + ao);
        }
#pragma unroll
        for (int x2 = 0; x2 < 2; ++x2) {
            int xl = xw + x2 * 16 + l16;
            if (ks < 4) {
                size_t bo = (size_t)((ks * 4 + quad) * 16384 + x0 + xl) * 8;
                bfh[x2] = *(const bf16x8*)(Bfh + bo);
            } else {
                int ko = (ks - 4) * 32 + quad * 8;
                bfh[x2] = *(const bf16x8*)&hsh[xl * CPAD + ko];
            }
        }
#pragma unroll
        for (int ot = 0; ot < 4; ++ot)
#pragma unroll
            for (int x2 = 0; x2 < 2; ++x2)
                acc[ot][x2] = __builtin_amdgcn_mfma_f32_16x16x32_bf16(afh[ot], bfh[x2], acc[ot][x2], 0, 0, 0);
    }
    __syncthreads();   // all LDS h reads done -> reuse hsh for C staging

#pragma unroll
    for (int ot = 0; ot < 4; ++ot) {
        float4 bc = *(const float4*)(bconv + lay * DIM + ot * 16 + quad * 4);
#pragma unroll
        for (int x2 = 0; x2 < 2; ++x2) {
            int xl = xw + x2 * 16 + l16;
            float vr[4] = {acc[ot][x2][0] + bc.x, acc[ot][x2][1] + bc.y,
                           acc[ot][x2][2] + bc.z, acc[ot][x2][3] + bc.w};
            if (!DO_MLP) {   // gelu between layers; final layer has no act
#pragma unroll
                for (int r = 0; r < 4; ++r) vr[r] = gelu_exact(vr[r]);
            }
            ushort4 uh;
            uh.x = to_bf16(vr[0]); uh.y = to_bf16(vr[1]);
            uh.z = to_bf16(vr[2]); uh.w = to_bf16(vr[3]);
            *(ushort4*)&hsh[xl * CPAD + ot * 16 + quad * 4] = uh;
        }
    }
    __syncthreads();

    if (!DO_MLP) {
#pragma unroll
        for (int it = 0; it < 4; ++it) {
            int idx = it * 256 + t;
            int row = idx >> 3, c8 = (idx & 7) * 8;
            size_t dst = ((size_t)(b << 14) + x0 + row) * 64 + c8;
            *(bf16x8*)(Hh + dst) = *(const bf16x8*)&hsh[row * CPAD + c8];
        }
        return;
    }

    // ---- fused final MLP (lay 2 only): out = gelu(h'@W1+b1)@W2 + b2 ----
#pragma unroll
    for (int x2 = 0; x2 < 2; ++x2) {
        bf16x8 ah[2];
#pragma unroll
        for (int ks = 0; ks < 2; ++ks) {
            int ro = (xw + x2 * 16 + l16) * CPAD + ks * 32 + quad * 8;
            ah[ks] = *(const bf16x8*)&hsh[ro];
        }
        float vo[4] = {0.f, 0.f, 0.f, 0.f};
#pragma unroll
        for (int ft = 0; ft < 8; ++ft) {
            f32x4 a2 = {};
#pragma unroll
            for (int ks = 0; ks < 2; ++ks) {
                size_t o = (size_t)(ft * 16 + l16) * 64 + ks * 32 + quad * 8;
                bf16x8 bh = *(const bf16x8*)(W1h + o);
                a2 = __builtin_amdgcn_mfma_f32_16x16x32_bf16(ah[ks], bh, a2, 0, 0, 0);
            }
            float bb = b1[ft * 16 + l16];
            float w2 = W2[ft * 16 + l16];
#pragma unroll
            for (int r = 0; r < 4; ++r)
                vo[r] += gelu_exact(a2[r] + bb) * w2;
        }
#pragma unroll
        for (int r = 0; r < 4; ++r) {
            float v = vo[r];
            v += __shfl_xor(v, 1);
            v += __shfl_xor(v, 2);
            v += __shfl_xor(v, 4);
            v += __shfl_xor(v, 8);
            vo[r] = v;
        }
        if (l16 == 0) {
            float bb2 = b2[0];
            float4 o4 = make_float4(vo[0] + bb2, vo[1] + bb2, vo[2] + bb2, vo[3] + bb2);
            *(float4*)(out + (size_t)b * NXX + x0 + xw + x2 * 16 + quad * 4) = o4;
        }
    }
}

// ---------------------------------------------------------------------------
extern "C" void kernel_launch(void* const* d_in, const int* in_sizes, int n_in,
                              void* d_out, int out_size, void* d_ws, size_t ws_size,
                              hipStream_t stream) {
    const float* x      = (const float*)d_in[0];
    const float* bases  = (const float*)d_in[1];
    const float* wbases = (const float*)d_in[2];
    const float* product= (const float*)d_in[3];
    const float* Dout   = (const float*)d_in[4];
    const float* Din    = (const float*)d_in[5];
    const float* A      = (const float*)d_in[6];
    const float* Bm     = (const float*)d_in[7];
    const float* Wsp    = (const float*)d_in[8];
    const float* Wconv  = (const float*)d_in[9];
    const float* bconv  = (const float*)d_in[10];
    const float* W0     = (const float*)d_in[11];
    const float* b0     = (const float*)d_in[12];
    const float* W1     = (const float*)d_in[13];
    const float* b1     = (const float*)d_in[14];
    const float* W2     = (const float*)d_in[15];
    const float* b2     = (const float*)d_in[16];
    float* out = (float*)d_out;

    const size_t need = 83656704;   // all-single-plane layout
    if (ws_size < need) {
        k_zero<<<dim3((out_size + 255) / 256), dim3(256), 0, stream>>>(out, out_size);
        return;
    }

    char* W = (char*)d_ws;
    size_t off = 0;
    auto alloc = [&](size_t bytes) { void* p = W + off; off += bytes; return p; };
    float* Hbuf     = (float*)alloc(1048576);
    u16*   bases_hi = (u16*)alloc(4194304);
    u16*   wbT_hi   = (u16*)alloc(4194304);
    u16*   wbT_lo   = (u16*)alloc(4194304);
    u16*   Abuf_hi  = (u16*)alloc(786432);
    float* ybuf     = (float*)alloc(1048576);
    float* xh       = (float*)alloc(1048576);   // must follow ybuf (joint zeroing)
    u16*   h_hi     = (u16*)alloc(67108864);
    u16*   w1t_hi   = (u16*)alloc(16384);

    k_build_H<<<dim3(1024), dim3(256), 0, stream>>>(Dout, Din, product, A, Bm, Hbuf);
    k_setup_bases<<<dim3(8192), dim3(256), 0, stream>>>(bases, bases_hi);
    k_setup_wbT<<<dim3(512, 4), dim3(256), 0, stream>>>(wbases, wbT_hi, wbT_lo);
    k_setup_w1t<<<dim3(32), dim3(256), 0, stream>>>(W1, w1t_hi);
    k_fc0<<<dim3(512, B_SZ), dim3(256), 0, stream>>>(x, W0, b0, h_hi);

    for (int lay = 0; lay < N_LAY; ++lay) {
        int last = (lay == N_LAY - 1);
        k_zero<<<dim3(2048), dim3(256), 0, stream>>>(ybuf, 524288);  // ybuf + xh
        k_spectral_mfma<<<dim3(B_SZ, 16), dim3(256), 0, stream>>>(
            h_hi, wbT_hi, wbT_lo, xh);
        k_hmix<<<dim3(B_SZ, JM), dim3(256), 0, stream>>>(xh, Hbuf, Wsp, ybuf, lay);
        k_build_A<<<dim3(B_SZ), dim3(256), 0, stream>>>(ybuf, Wconv, Abuf_hi, lay);
        dim3 g(B_SZ, 128), blk(256);
        if (last)
            k_inv_conv_mfma<true><<<g, blk, 0, stream>>>(
                Abuf_hi, bases_hi, h_hi, bconv, lay,
                w1t_hi, b1, W2, b2, out);
        else
            k_inv_conv_mfma<false><<<g, blk, 0, stream>>>(
                Abuf_hi, bases_hi, h_hi, bconv, lay,
                w1t_hi, b1, W2, b2, out);
    }
}

// Round 10
// 595.883 us; speedup vs baseline: 1.6178x; 1.1557x over previous
//
#include <hip/hip_runtime.h>
#include <hip/hip_bf16.h>
#include <math.h>

#define B_SZ   32
#define NXX    16384
#define IN_DIM 3
#define DIM    64
#define JM     16
#define MODE   128
#define RANKK  4
#define FC_DIM 128
#define N_LAY  3

typedef __attribute__((ext_vector_type(8))) short bf16x8;
typedef __attribute__((ext_vector_type(4))) float f32x4;
typedef unsigned short u16;

// Fast gelu: tanh-form == v * sigmoid(2u), u = sqrt(2/pi)*(v + 0.044715 v^3).
// v_exp + v_rcp hardware ops; max |diff vs exact erf-gelu| ~3e-4.
// Inf-safe: e=inf -> rcp(inf)=0 -> result 0 (v<<0); e=0 -> result v (v>>0).
__device__ __forceinline__ float gelu_fast(float v) {
    float p = v * (0.7978845608f + 0.0356774081f * v * v);
    float e = __expf(-2.f * p);
    return v * __builtin_amdgcn_rcpf(1.f + e);
}
__device__ __forceinline__ void split_bf16(float v, u16& h, u16& l) {
    __hip_bfloat16 bh = __float2bfloat16(v);
    float fh = __bfloat162float(bh);
    __hip_bfloat16 bl = __float2bfloat16(v - fh);
    h = *(u16*)&bh;
    l = *(u16*)&bl;
}
__device__ __forceinline__ u16 to_bf16(float v) {
    __hip_bfloat16 b = __float2bfloat16(v);
    return *(u16*)&b;
}

// ---------------------------------------------------------------------------
__global__ __launch_bounds__(256) void k_zero(float* __restrict__ p, int n) {
    int i = blockIdx.x * 256 + threadIdx.x;
    if (i < n) p[i] = 0.f;
}

// H[j,k,l] = D_out[j,k]*D_in[j,l]*product[k,l] + sum_r A[j,r,k]*Bm[j,r,l]
__global__ __launch_bounds__(256) void k_build_H(
        const float* __restrict__ Dout, const float* __restrict__ Din,
        const float* __restrict__ product, const float* __restrict__ A,
        const float* __restrict__ Bm, float* __restrict__ H) {
    int idx = blockIdx.x * 256 + threadIdx.x;
    int j = idx >> 14;
    int k = (idx >> 7) & 127;
    int l = idx & 127;
    float v = Dout[j * MODE + k] * Din[j * MODE + l] * product[k * MODE + l];
#pragma unroll
    for (int r = 0; r < RANKK; ++r)
        v += A[(j * RANKK + r) * MODE + k] * Bm[(j * RANKK + r) * MODE + l];
    H[idx] = v;
}

// bases (fp32 [x][k]) -> FRAG-MAJOR single bf16 plane:
//   Bf[(k>>3)*131072 + x*8 + (k&7)]   grid 8192 x 256.
__global__ __launch_bounds__(256) void k_setup_bases(
        const float* __restrict__ bases, u16* __restrict__ bh) {
    int idx = blockIdx.x * 256 + threadIdx.x;
    int x = idx >> 7, k = idx & 127;
    size_t off = (size_t)(k >> 3) * 131072 + (size_t)x * 8 + (k & 7);
    bh[off] = to_bf16(bases[idx]);
}

// wbT[l][x] = wbases[x][l], single bf16 plane.  grid (512, 4) x 256, LDS-tiled.
__global__ __launch_bounds__(256) void k_setup_wbT(
        const float* __restrict__ wb, u16* __restrict__ Th) {
    __shared__ float tile[32][33];
    int bx = blockIdx.x, bl = blockIdx.y;
    int t = threadIdx.x;
    int i = t >> 5, jj = t & 31;
#pragma unroll
    for (int r = 0; r < 4; ++r)
        tile[i + r * 8][jj] = wb[(size_t)(bx * 32 + i + r * 8) * MODE + bl * 32 + jj];
    __syncthreads();
#pragma unroll
    for (int r = 0; r < 4; ++r) {
        int l = bl * 32 + i + r * 8;
        int x = bx * 32 + jj;
        Th[(size_t)l * NXX + x] = to_bf16(tile[jj][i + r * 8]);
    }
}

// W1T[f*64+c] = W1[c*128+f] single bf16 plane.  grid 32 x 256
__global__ __launch_bounds__(256) void k_setup_w1t(
        const float* __restrict__ W1, u16* __restrict__ wh) {
    int i = blockIdx.x * 256 + threadIdx.x;
    int f = i >> 6, c = i & 63;
    wh[i] = to_bf16(W1[c * FC_DIM + f]);
}

// fc0: h[b,x,c] (single bf16 plane), coalesced ushort8 stores.
// grid (512, 32) x 256.
__global__ __launch_bounds__(256) void k_fc0(
        const float* __restrict__ x, const float* __restrict__ W0,
        const float* __restrict__ b0, u16* __restrict__ hh) {
    __shared__ float w0s[IN_DIM * DIM + DIM];
    int t = threadIdx.x;
    if (t < IN_DIM * DIM) w0s[t] = W0[t];
    if (t < DIM) w0s[IN_DIM * DIM + t] = b0[t];
    __syncthreads();
    int b = blockIdx.y;
    int xi = blockIdx.x * 32 + (t >> 3);
    int c8 = (t & 7) * 8;
    const float* xp = x + ((size_t)b * NXX + xi) * IN_DIM;
    float x0 = xp[0], x1 = xp[1], x2 = xp[2];
    u16 rh[8];
#pragma unroll
    for (int i = 0; i < 8; ++i) {
        int c = c8 + i;
        float v = x0 * w0s[c] + x1 * w0s[DIM + c] + x2 * w0s[2 * DIM + c]
                + w0s[3 * DIM + c];
        rh[i] = to_bf16(v);
    }
    size_t o = ((size_t)(b << 14) + xi) * 64 + c8;
    *(ushort4*)(hh + o)     = make_ushort4(rh[0], rh[1], rh[2], rh[3]);
    *(ushort4*)(hh + o + 4) = make_ushort4(rh[4], rh[5], rh[6], rh[7]);
}

// ---------------------------------------------------------------------------
// Spectral via MFMA: xh[b][c][l] += sum_x h[b][x][c] * wbases[x][l]
// h and wbases single bf16 planes.  Rotation-swizzled LDS transpose.
// grid (32 b, 16 ks) x 256 (4 waves; wave = 16c x 32l).
#define SPAD 72
__global__ __launch_bounds__(256) void k_spectral_mfma(
        const u16* __restrict__ Hh,
        const u16* __restrict__ Wh,
        float* __restrict__ xh) {
    __shared__ u16 Ash[64 * SPAD];
    int t = threadIdx.x;
    int wave = t >> 6, lane = t & 63, quad = lane >> 4, l16 = lane & 15;
    int b = blockIdx.x;
    int x0 = blockIdx.y * 1024;
    int cq = (t & 15) * 4;
    int xq = (t >> 4) * 4;
    int colw = (xq + ((t & 7) << 3)) & 63;
    const u16* srch = Hh + ((size_t)(b << 14) + x0 + xq) * 64 + cq;
    int l0 = wave * 32;
    const u16* w0h = Wh + (size_t)(l0 + l16) * NXX + x0;
    const u16* w1h = Wh + (size_t)(l0 + 16 + l16) * NXX + x0;
    f32x4 acc[4][2] = {};
    for (int kt = 0; kt < 1024; kt += 64) {
        __syncthreads();
        {
            const u16* s = srch + (size_t)kt * 64;
            ushort4 r0 = *(const ushort4*)(s);
            ushort4 r1 = *(const ushort4*)(s + 64);
            ushort4 r2 = *(const ushort4*)(s + 128);
            ushort4 r3 = *(const ushort4*)(s + 192);
            *(ushort4*)&Ash[(cq + 0) * SPAD + colw] = make_ushort4(r0.x, r1.x, r2.x, r3.x);
            *(ushort4*)&Ash[(cq + 1) * SPAD + colw] = make_ushort4(r0.y, r1.y, r2.y, r3.y);
            *(ushort4*)&Ash[(cq + 2) * SPAD + colw] = make_ushort4(r0.z, r1.z, r2.z, r3.z);
            *(ushort4*)&Ash[(cq + 3) * SPAD + colw] = make_ushort4(r0.w, r1.w, r2.w, r3.w);
        }
        __syncthreads();
#pragma unroll
        for (int k0 = 0; k0 < 64; k0 += 32) {
            bf16x8 afh[4];
#pragma unroll
            for (int ct = 0; ct < 4; ++ct) {
                int rr = ct * 16 + l16;
                int ro = rr * SPAD + (((k0 + quad * 8) + (((rr >> 2) & 7) << 3)) & 63);
                afh[ct] = *(const bf16x8*)&Ash[ro];
            }
            int go = kt + k0 + quad * 8;
            bf16x8 b0h = *(const bf16x8*)(w0h + go);
            bf16x8 b1h = *(const bf16x8*)(w1h + go);
#pragma unroll
            for (int ct = 0; ct < 4; ++ct) {
                acc[ct][0] = __builtin_amdgcn_mfma_f32_16x16x32_bf16(afh[ct], b0h, acc[ct][0], 0, 0, 0);
                acc[ct][1] = __builtin_amdgcn_mfma_f32_16x16x32_bf16(afh[ct], b1h, acc[ct][1], 0, 0, 0);
            }
        }
    }
    float* xb = xh + (size_t)(b << 6) * 128;
#pragma unroll
    for (int ct = 0; ct < 4; ++ct)
#pragma unroll
        for (int lt = 0; lt < 2; ++lt)
#pragma unroll
            for (int r = 0; r < 4; ++r)
                atomicAdd(xb + (size_t)(ct * 16 + quad * 4 + r) * 128 + l0 + lt * 16 + l16,
                          acc[ct][lt][r]);
}

// ---------------------------------------------------------------------------
// Fused H-mix + channel contraction.  grid (32, 16) x 256
__global__ __launch_bounds__(256) void k_hmix(
        const float* __restrict__ xh, const float* __restrict__ H,
        const float* __restrict__ Wsp, float* __restrict__ y, int lay) {
    __shared__ float xs[DIM][132];
    __shared__ float Ts[DIM][MODE];
    __shared__ float Ws[DIM][DIM];
    int t = threadIdx.x;
    int b = blockIdx.x;
    int j = blockIdx.y;
    const float* xb = xh + (size_t)b * DIM * MODE;
    for (int idx = t; idx < DIM * MODE; idx += 256)
        xs[idx >> 7][idx & 127] = xb[idx];
    const float* Wl = Wsp + (size_t)lay * DIM * DIM * JM + j;
    for (int idx = t; idx < DIM * DIM; idx += 256)
        Ws[idx >> 6][idx & 63] = Wl[(size_t)idx * JM];
    __syncthreads();
    {
        int k4 = (t & 31) * 4;
        int i0 = (t >> 5) * 8;
        float acc[8][4] = {};
        const float* Hbase = H + ((size_t)j * MODE + k4) * MODE;
        for (int l = 0; l < MODE; l += 4) {
            float4 hv0 = *(const float4*)(Hbase + 0 * MODE + l);
            float4 hv1 = *(const float4*)(Hbase + 1 * MODE + l);
            float4 hv2 = *(const float4*)(Hbase + 2 * MODE + l);
            float4 hv3 = *(const float4*)(Hbase + 3 * MODE + l);
#pragma unroll
            for (int ii = 0; ii < 8; ++ii) {
                float4 xv = *(const float4*)&xs[i0 + ii][l];
                acc[ii][0] += hv0.x * xv.x + hv0.y * xv.y + hv0.z * xv.z + hv0.w * xv.w;
                acc[ii][1] += hv1.x * xv.x + hv1.y * xv.y + hv1.z * xv.z + hv1.w * xv.w;
                acc[ii][2] += hv2.x * xv.x + hv2.y * xv.y + hv2.z * xv.z + hv2.w * xv.w;
                acc[ii][3] += hv3.x * xv.x + hv3.y * xv.y + hv3.z * xv.z + hv3.w * xv.w;
            }
        }
#pragma unroll
        for (int ii = 0; ii < 8; ++ii)
            *(float4*)&Ts[i0 + ii][k4] = make_float4(acc[ii][0], acc[ii][1], acc[ii][2], acc[ii][3]);
    }
    __syncthreads();
    {
        int k = t & 127;
        int o0 = (t >> 7) * 32;
        float acc2[32] = {};
        for (int i = 0; i < DIM; ++i) {
            float tv = Ts[i][k];
            const float* wr = &Ws[i][o0];
#pragma unroll
            for (int o4 = 0; o4 < 32; o4 += 4) {
                float4 wv = *(const float4*)(wr + o4);
                acc2[o4 + 0] += wv.x * tv;
                acc2[o4 + 1] += wv.y * tv;
                acc2[o4 + 2] += wv.z * tv;
                acc2[o4 + 3] += wv.w * tv;
            }
        }
        float* yp = y + ((size_t)b * DIM + o0) * MODE + k;
#pragma unroll
        for (int o = 0; o < 32; ++o)
            atomicAdd(yp + (size_t)o * MODE, acc2[o]);
    }
}

// A buffer in FRAG-MAJOR layout (y|Wconv, single bf16 plane).  grid (32) x 256
__global__ __launch_bounds__(256) void k_build_A(
        const float* __restrict__ y, const float* __restrict__ Wconv,
        u16* __restrict__ Ah, int lay) {
    int b = blockIdx.x;
    for (int idx = threadIdx.x; idx < 12288; idx += 256) {
        int i = idx & 7, l16 = (idx >> 3) & 15, quad = (idx >> 7) & 3,
            ot = (idx >> 9) & 3, ks = idx >> 11;
        int o = ot * 16 + l16;
        int k = ks * 32 + quad * 8 + i;
        float v = (k < 128) ? y[((size_t)b * DIM + o) * MODE + k]
                            : Wconv[(size_t)lay * DIM * DIM + o * DIM + (k - 128)];
        Ah[(size_t)b * 12288 + idx] = to_bf16(v);
    }
}

// ---------------------------------------------------------------------------
// inv_conv v6: h' = act(A(64x192) @ B(192 x 128x) + bconv), in-place on h.
// ALL single bf16 plane (A, bases, h) -> 1 MFMA per frag pair, 48 MFMA/wave.
// DO_MLP (compile-time): lay2 computes final MLP from LDS tile (W1 bf16),
// skips writeback.  grid (32 b, 128 xt) x 256 (4 waves; wave = 64o x 32x).
#define CPAD 72
template <bool DO_MLP>
__global__ __launch_bounds__(256, 4) void k_inv_conv_mfma(
        const u16* __restrict__ Afh,
        const u16* __restrict__ Bfh,
        u16* __restrict__ Hh,
        const float* __restrict__ bconv, int lay,
        const u16* __restrict__ W1h,
        const float* __restrict__ b1, const float* __restrict__ W2,
        const float* __restrict__ b2, float* __restrict__ out) {
    __shared__ u16 hsh[128 * CPAD];
    int t = threadIdx.x;
    int wave = t >> 6, lane = t & 63, quad = lane >> 4, l16 = lane & 15;
    int b = blockIdx.x;
    int x0 = blockIdx.y * 128;
#pragma unroll
    for (int it = 0; it < 4; ++it) {
        int idx = it * 256 + t;
        int row = idx >> 3, c8 = (idx & 7) * 8;
        size_t src = ((size_t)(b << 14) + x0 + row) * 64 + c8;
        *(bf16x8*)&hsh[row * CPAD + c8] = *(const bf16x8*)(Hh + src);
    }
    __syncthreads();

    int xw = wave * 32;
    const u16* afb_h = Afh + (size_t)b * 12288;
    f32x4 acc[4][2] = {};
#pragma unroll
    for (int ks = 0; ks < 6; ++ks) {
        bf16x8 afh[4], bfh[2];
#pragma unroll
        for (int ot = 0; ot < 4; ++ot) {
            size_t ao = (size_t)(((ks * 4 + ot) * 4 + quad) * 16 + l16) * 8;
            afh[ot] = *(const bf16x8*)(afb_h + ao);
        }
#pragma unroll
        for (int x2 = 0; x2 < 2; ++x2) {
            int xl = xw + x2 * 16 + l16;
            if (ks < 4) {
                size_t bo = (size_t)((ks * 4 + quad) * 16384 + x0 + xl) * 8;
                bfh[x2] = *(const bf16x8*)(Bfh + bo);
            } else {
                int ko = (ks - 4) * 32 + quad * 8;
                bfh[x2] = *(const bf16x8*)&hsh[xl * CPAD + ko];
            }
        }
#pragma unroll
        for (int ot = 0; ot < 4; ++ot)
#pragma unroll
            for (int x2 = 0; x2 < 2; ++x2)
                acc[ot][x2] = __builtin_amdgcn_mfma_f32_16x16x32_bf16(afh[ot], bfh[x2], acc[ot][x2], 0, 0, 0);
    }
    __syncthreads();   // all LDS h reads done -> reuse hsh for C staging

#pragma unroll
    for (int ot = 0; ot < 4; ++ot) {
        float4 bc = *(const float4*)(bconv + lay * DIM + ot * 16 + quad * 4);
#pragma unroll
        for (int x2 = 0; x2 < 2; ++x2) {
            int xl = xw + x2 * 16 + l16;
            float vr[4] = {acc[ot][x2][0] + bc.x, acc[ot][x2][1] + bc.y,
                           acc[ot][x2][2] + bc.z, acc[ot][x2][3] + bc.w};
            if (!DO_MLP) {   // gelu between layers; final layer has no act
#pragma unroll
                for (int r = 0; r < 4; ++r) vr[r] = gelu_fast(vr[r]);
            }
            ushort4 uh;
            uh.x = to_bf16(vr[0]); uh.y = to_bf16(vr[1]);
            uh.z = to_bf16(vr[2]); uh.w = to_bf16(vr[3]);
            *(ushort4*)&hsh[xl * CPAD + ot * 16 + quad * 4] = uh;
        }
    }
    __syncthreads();

    if (!DO_MLP) {
#pragma unroll
        for (int it = 0; it < 4; ++it) {
            int idx = it * 256 + t;
            int row = idx >> 3, c8 = (idx & 7) * 8;
            size_t dst = ((size_t)(b << 14) + x0 + row) * 64 + c8;
            *(bf16x8*)(Hh + dst) = *(const bf16x8*)&hsh[row * CPAD + c8];
        }
        return;
    }

    // ---- fused final MLP (lay 2 only): out = gelu(h'@W1+b1)@W2 + b2 ----
#pragma unroll
    for (int x2 = 0; x2 < 2; ++x2) {
        bf16x8 ah[2];
#pragma unroll
        for (int ks = 0; ks < 2; ++ks) {
            int ro = (xw + x2 * 16 + l16) * CPAD + ks * 32 + quad * 8;
            ah[ks] = *(const bf16x8*)&hsh[ro];
        }
        float vo[4] = {0.f, 0.f, 0.f, 0.f};
#pragma unroll
        for (int ft = 0; ft < 8; ++ft) {
            f32x4 a2 = {};
#pragma unroll
            for (int ks = 0; ks < 2; ++ks) {
                size_t o = (size_t)(ft * 16 + l16) * 64 + ks * 32 + quad * 8;
                bf16x8 bh = *(const bf16x8*)(W1h + o);
                a2 = __builtin_amdgcn_mfma_f32_16x16x32_bf16(ah[ks], bh, a2, 0, 0, 0);
            }
            float bb = b1[ft * 16 + l16];
            float w2 = W2[ft * 16 + l16];
#pragma unroll
            for (int r = 0; r < 4; ++r)
                vo[r] += gelu_fast(a2[r] + bb) * w2;
        }
#pragma unroll
        for (int r = 0; r < 4; ++r) {
            float v = vo[r];
            v += __shfl_xor(v, 1);
            v += __shfl_xor(v, 2);
            v += __shfl_xor(v, 4);
            v += __shfl_xor(v, 8);
            vo[r] = v;
        }
        if (l16 == 0) {
            float bb2 = b2[0];
            float4 o4 = make_float4(vo[0] + bb2, vo[1] + bb2, vo[2] + bb2, vo[3] + bb2);
            *(float4*)(out + (size_t)b * NXX + x0 + xw + x2 * 16 + quad * 4) = o4;
        }
    }
}

// ---------------------------------------------------------------------------
extern "C" void kernel_launch(void* const* d_in, const int* in_sizes, int n_in,
                              void* d_out, int out_size, void* d_ws, size_t ws_size,
                              hipStream_t stream) {
    const float* x      = (const float*)d_in[0];
    const float* bases  = (const float*)d_in[1];
    const float* wbases = (const float*)d_in[2];
    const float* product= (const float*)d_in[3];
    const float* Dout   = (const float*)d_in[4];
    const float* Din    = (const float*)d_in[5];
    const float* A      = (const float*)d_in[6];
    const float* Bm     = (const float*)d_in[7];
    const float* Wsp    = (const float*)d_in[8];
    const float* Wconv  = (const float*)d_in[9];
    const float* bconv  = (const float*)d_in[10];
    const float* W0     = (const float*)d_in[11];
    const float* b0     = (const float*)d_in[12];
    const float* W1     = (const float*)d_in[13];
    const float* b1     = (const float*)d_in[14];
    const float* W2     = (const float*)d_in[15];
    const float* b2     = (const float*)d_in[16];
    float* out = (float*)d_out;

    const size_t need = 79462400;   // single-plane everything
    if (ws_size < need) {
        k_zero<<<dim3((out_size + 255) / 256), dim3(256), 0, stream>>>(out, out_size);
        return;
    }

    char* W = (char*)d_ws;
    size_t off = 0;
    auto alloc = [&](size_t bytes) { void* p = W + off; off += bytes; return p; };
    float* Hbuf     = (float*)alloc(1048576);
    u16*   bases_hi = (u16*)alloc(4194304);
    u16*   wbT_hi   = (u16*)alloc(4194304);
    u16*   Abuf_hi  = (u16*)alloc(786432);
    float* ybuf     = (float*)alloc(1048576);
    float* xh       = (float*)alloc(1048576);   // must follow ybuf (joint zeroing)
    u16*   h_hi     = (u16*)alloc(67108864);
    u16*   w1t_hi   = (u16*)alloc(16384);

    k_build_H<<<dim3(1024), dim3(256), 0, stream>>>(Dout, Din, product, A, Bm, Hbuf);
    k_setup_bases<<<dim3(8192), dim3(256), 0, stream>>>(bases, bases_hi);
    k_setup_wbT<<<dim3(512, 4), dim3(256), 0, stream>>>(wbases, wbT_hi);
    k_setup_w1t<<<dim3(32), dim3(256), 0, stream>>>(W1, w1t_hi);
    k_fc0<<<dim3(512, B_SZ), dim3(256), 0, stream>>>(x, W0, b0, h_hi);

    for (int lay = 0; lay < N_LAY; ++lay) {
        int last = (lay == N_LAY - 1);
        k_zero<<<dim3(2048), dim3(256), 0, stream>>>(ybuf, 524288);  // ybuf + xh
        k_spectral_mfma<<<dim3(B_SZ, 16), dim3(256), 0, stream>>>(
            h_hi, wbT_hi, xh);
        k_hmix<<<dim3(B_SZ, JM), dim3(256), 0, stream>>>(xh, Hbuf, Wsp, ybuf, lay);
        k_build_A<<<dim3(B_SZ), dim3(256), 0, stream>>>(ybuf, Wconv, Abuf_hi, lay);
        dim3 g(B_SZ, 128), blk(256);
        if (last)
            k_inv_conv_mfma<true><<<g, blk, 0, stream>>>(
                Abuf_hi, bases_hi, h_hi, bconv, lay,
                w1t_hi, b1, W2, b2, out);
        else
            k_inv_conv_mfma<false><<<g, blk, 0, stream>>>(
                Abuf_hi, bases_hi, h_hi, bconv, lay,
                w1t_hi, b1, W2, b2, out);
    }
}

// Round 11
// 496.270 us; speedup vs baseline: 1.9425x; 1.2007x over previous
//
#include <hip/hip_runtime.h>
#include <hip/hip_bf16.h>
#include <math.h>

#define B_SZ   32
#define NXX    16384
#define IN_DIM 3
#define DIM    64
#define JM     16
#define MODE   128
#define RANKK  4
#define FC_DIM 128
#define N_LAY  3

typedef __attribute__((ext_vector_type(8))) short bf16x8;
typedef __attribute__((ext_vector_type(4))) float f32x4;
typedef unsigned short u16;

// Fast gelu: v * sigmoid(2u), u = sqrt(2/pi)*(v + 0.044715 v^3).
__device__ __forceinline__ float gelu_fast(float v) {
    float p = v * (0.7978845608f + 0.0356774081f * v * v);
    float e = __expf(-2.f * p);
    return v * __builtin_amdgcn_rcpf(1.f + e);
}
__device__ __forceinline__ u16 to_bf16(float v) {
    __hip_bfloat16 b = __float2bfloat16(v);
    return *(u16*)&b;
}

// ---------------------------------------------------------------------------
__global__ __launch_bounds__(256) void k_zero(float* __restrict__ p, int n) {
    int i = blockIdx.x * 256 + threadIdx.x;
    if (i < n) p[i] = 0.f;
}

// H[j,k,l] bf16 row-major (l contig = A-frag-ready for m=k, kk=l).
__global__ __launch_bounds__(256) void k_build_H(
        const float* __restrict__ Dout, const float* __restrict__ Din,
        const float* __restrict__ product, const float* __restrict__ A,
        const float* __restrict__ Bm, u16* __restrict__ Hbf) {
    int idx = blockIdx.x * 256 + threadIdx.x;
    int j = idx >> 14;
    int k = (idx >> 7) & 127;
    int l = idx & 127;
    float v = Dout[j * MODE + k] * Din[j * MODE + l] * product[k * MODE + l];
#pragma unroll
    for (int r = 0; r < RANKK; ++r)
        v += A[(j * RANKK + r) * MODE + k] * Bm[(j * RANKK + r) * MODE + l];
    Hbf[idx] = to_bf16(v);
}

// WsT[lay][j][o][i] = Wsp[lay][i][o][j] bf16 (i contig).  grid 768 x 256.
__global__ __launch_bounds__(256) void k_setup_wst(
        const float* __restrict__ Wsp, u16* __restrict__ WsT) {
    int idx = blockIdx.x * 256 + threadIdx.x;   // ((lay*16+j)*64+o)*64+i
    int i = idx & 63, o = (idx >> 6) & 63, j = (idx >> 12) & 15, lay = idx >> 16;
    WsT[idx] = to_bf16(Wsp[(((size_t)lay * 64 + i) * 64 + o) * 16 + j]);
}

// bases (fp32 [x][k]) -> FRAG-MAJOR single bf16 plane.  grid 8192 x 256.
__global__ __launch_bounds__(256) void k_setup_bases(
        const float* __restrict__ bases, u16* __restrict__ bh) {
    int idx = blockIdx.x * 256 + threadIdx.x;
    int x = idx >> 7, k = idx & 127;
    size_t off = (size_t)(k >> 3) * 131072 + (size_t)x * 8 + (k & 7);
    bh[off] = to_bf16(bases[idx]);
}

// wbT[l][x] = wbases[x][l], single bf16 plane.  grid (512, 4) x 256, LDS-tiled.
__global__ __launch_bounds__(256) void k_setup_wbT(
        const float* __restrict__ wb, u16* __restrict__ Th) {
    __shared__ float tile[32][33];
    int bx = blockIdx.x, bl = blockIdx.y;
    int t = threadIdx.x;
    int i = t >> 5, jj = t & 31;
#pragma unroll
    for (int r = 0; r < 4; ++r)
        tile[i + r * 8][jj] = wb[(size_t)(bx * 32 + i + r * 8) * MODE + bl * 32 + jj];
    __syncthreads();
#pragma unroll
    for (int r = 0; r < 4; ++r) {
        int l = bl * 32 + i + r * 8;
        int x = bx * 32 + jj;
        Th[(size_t)l * NXX + x] = to_bf16(tile[jj][i + r * 8]);
    }
}

// W1T[f*64+c] = W1[c*128+f] single bf16 plane.  grid 32 x 256
__global__ __launch_bounds__(256) void k_setup_w1t(
        const float* __restrict__ W1, u16* __restrict__ wh) {
    int i = blockIdx.x * 256 + threadIdx.x;
    int f = i >> 6, c = i & 63;
    wh[i] = to_bf16(W1[c * FC_DIM + f]);
}

// fc0: h[b,x,c] (single bf16 plane), coalesced ushort8 stores.
// grid (512, 32) x 256.
__global__ __launch_bounds__(256) void k_fc0(
        const float* __restrict__ x, const float* __restrict__ W0,
        const float* __restrict__ b0, u16* __restrict__ hh) {
    __shared__ float w0s[IN_DIM * DIM + DIM];
    int t = threadIdx.x;
    if (t < IN_DIM * DIM) w0s[t] = W0[t];
    if (t < DIM) w0s[IN_DIM * DIM + t] = b0[t];
    __syncthreads();
    int b = blockIdx.y;
    int xi = blockIdx.x * 32 + (t >> 3);
    int c8 = (t & 7) * 8;
    const float* xp = x + ((size_t)b * NXX + xi) * IN_DIM;
    float x0 = xp[0], x1 = xp[1], x2 = xp[2];
    u16 rh[8];
#pragma unroll
    for (int i = 0; i < 8; ++i) {
        int c = c8 + i;
        float v = x0 * w0s[c] + x1 * w0s[DIM + c] + x2 * w0s[2 * DIM + c]
                + w0s[3 * DIM + c];
        rh[i] = to_bf16(v);
    }
    size_t o = ((size_t)(b << 14) + xi) * 64 + c8;
    *(ushort4*)(hh + o)     = make_ushort4(rh[0], rh[1], rh[2], rh[3]);
    *(ushort4*)(hh + o + 4) = make_ushort4(rh[4], rh[5], rh[6], rh[7]);
}

// ---------------------------------------------------------------------------
// Spectral via MFMA: xh[b][c][l] += sum_x h[b][x][c] * wbases[x][l]
// grid (32 b, 32 ks) x 256 (4 waves; wave = 16c x 32l), 512-x slab per block.
#define SPAD 72
__global__ __launch_bounds__(256) void k_spectral_mfma(
        const u16* __restrict__ Hh,
        const u16* __restrict__ Wh,
        float* __restrict__ xh) {
    __shared__ u16 Ash[64 * SPAD];
    int t = threadIdx.x;
    int wave = t >> 6, lane = t & 63, quad = lane >> 4, l16 = lane & 15;
    int b = blockIdx.x;
    int x0 = blockIdx.y * 512;
    int cq = (t & 15) * 4;
    int xq = (t >> 4) * 4;
    int colw = (xq + ((t & 7) << 3)) & 63;
    const u16* srch = Hh + ((size_t)(b << 14) + x0 + xq) * 64 + cq;
    int l0 = wave * 32;
    const u16* w0h = Wh + (size_t)(l0 + l16) * NXX + x0;
    const u16* w1h = Wh + (size_t)(l0 + 16 + l16) * NXX + x0;
    f32x4 acc[4][2] = {};
    for (int kt = 0; kt < 512; kt += 64) {
        __syncthreads();
        {
            const u16* s = srch + (size_t)kt * 64;
            ushort4 r0 = *(const ushort4*)(s);
            ushort4 r1 = *(const ushort4*)(s + 64);
            ushort4 r2 = *(const ushort4*)(s + 128);
            ushort4 r3 = *(const ushort4*)(s + 192);
            *(ushort4*)&Ash[(cq + 0) * SPAD + colw] = make_ushort4(r0.x, r1.x, r2.x, r3.x);
            *(ushort4*)&Ash[(cq + 1) * SPAD + colw] = make_ushort4(r0.y, r1.y, r2.y, r3.y);
            *(ushort4*)&Ash[(cq + 2) * SPAD + colw] = make_ushort4(r0.z, r1.z, r2.z, r3.z);
            *(ushort4*)&Ash[(cq + 3) * SPAD + colw] = make_ushort4(r0.w, r1.w, r2.w, r3.w);
        }
        __syncthreads();
#pragma unroll
        for (int k0 = 0; k0 < 64; k0 += 32) {
            bf16x8 afh[4];
#pragma unroll
            for (int ct = 0; ct < 4; ++ct) {
                int rr = ct * 16 + l16;
                int ro = rr * SPAD + (((k0 + quad * 8) + (((rr >> 2) & 7) << 3)) & 63);
                afh[ct] = *(const bf16x8*)&Ash[ro];
            }
            int go = kt + k0 + quad * 8;
            bf16x8 b0h = *(const bf16x8*)(w0h + go);
            bf16x8 b1h = *(const bf16x8*)(w1h + go);
#pragma unroll
            for (int ct = 0; ct < 4; ++ct) {
                acc[ct][0] = __builtin_amdgcn_mfma_f32_16x16x32_bf16(afh[ct], b0h, acc[ct][0], 0, 0, 0);
                acc[ct][1] = __builtin_amdgcn_mfma_f32_16x16x32_bf16(afh[ct], b1h, acc[ct][1], 0, 0, 0);
            }
        }
    }
    float* xb = xh + (size_t)(b << 6) * 128;
#pragma unroll
    for (int ct = 0; ct < 4; ++ct)
#pragma unroll
        for (int lt = 0; lt < 2; ++lt)
#pragma unroll
            for (int r = 0; r < 4; ++r)
                atomicAdd(xb + (size_t)(ct * 16 + quad * 4 + r) * 128 + l0 + lt * 16 + l16,
                          acc[ct][lt][r]);
}

// ---------------------------------------------------------------------------
// hmix via MFMA.  One block per (b, j):
//   phase 1: T[k][i] = sum_l H[j][k][l] * xh[b][i][l]   (A=Hbf, B=xh-bf16 LDS)
//   phase 2: y[b][o][k] += sum_i WsT[j][o][i] * T[k][i] (atomics over j)
// grid (32, 16) x 256 (4 waves; wave = 32k of the 128k output).
#define XPAD 136
#define TPAD 72
__global__ __launch_bounds__(256) void k_hmix_mfma(
        const float* __restrict__ xh, const u16* __restrict__ Hbf,
        const u16* __restrict__ WsT, float* __restrict__ y, int lay) {
    __shared__ u16 xsb[64 * XPAD];   // [i][l]
    __shared__ u16 Ts[128 * TPAD];   // [k][i]
    int t = threadIdx.x;
    int wave = t >> 6, lane = t & 63, quad = lane >> 4, l16 = lane & 15;
    int b = blockIdx.x, j = blockIdx.y;
    const float* xb = xh + (size_t)b * DIM * MODE;
    for (int idx = t; idx < DIM * MODE; idx += 256)
        xsb[(idx >> 7) * XPAD + (idx & 127)] = to_bf16(xb[idx]);
    __syncthreads();
    int k_base = wave * 32;
    // phase 1
    {
        f32x4 acc[2][4] = {};
        const u16* Hj = Hbf + (size_t)j * MODE * MODE;
#pragma unroll
        for (int l0 = 0; l0 < 128; l0 += 32) {
            bf16x8 af[2], bf[4];
#pragma unroll
            for (int mt = 0; mt < 2; ++mt)
                af[mt] = *(const bf16x8*)(Hj + (size_t)(k_base + mt * 16 + l16) * 128 + l0 + quad * 8);
#pragma unroll
            for (int nt = 0; nt < 4; ++nt)
                bf[nt] = *(const bf16x8*)&xsb[(nt * 16 + l16) * XPAD + l0 + quad * 8];
#pragma unroll
            for (int mt = 0; mt < 2; ++mt)
#pragma unroll
                for (int nt = 0; nt < 4; ++nt)
                    acc[mt][nt] = __builtin_amdgcn_mfma_f32_16x16x32_bf16(af[mt], bf[nt], acc[mt][nt], 0, 0, 0);
        }
#pragma unroll
        for (int mt = 0; mt < 2; ++mt)
#pragma unroll
            for (int nt = 0; nt < 4; ++nt)
#pragma unroll
                for (int r = 0; r < 4; ++r)
                    Ts[(k_base + mt * 16 + quad * 4 + r) * TPAD + nt * 16 + l16] =
                        to_bf16(acc[mt][nt][r]);
    }
    __syncthreads();
    // phase 2
    {
        f32x4 acc[4][2] = {};
        const u16* Wj = WsT + ((size_t)lay * JM + j) * DIM * DIM;
#pragma unroll
        for (int i0 = 0; i0 < 64; i0 += 32) {
            bf16x8 af[4], bf[2];
#pragma unroll
            for (int mt = 0; mt < 4; ++mt)
                af[mt] = *(const bf16x8*)(Wj + (size_t)(mt * 16 + l16) * 64 + i0 + quad * 8);
#pragma unroll
            for (int nt = 0; nt < 2; ++nt)
                bf[nt] = *(const bf16x8*)&Ts[(k_base + nt * 16 + l16) * TPAD + i0 + quad * 8];
#pragma unroll
            for (int mt = 0; mt < 4; ++mt)
#pragma unroll
                for (int nt = 0; nt < 2; ++nt)
                    acc[mt][nt] = __builtin_amdgcn_mfma_f32_16x16x32_bf16(af[mt], bf[nt], acc[mt][nt], 0, 0, 0);
        }
        float* yb = y + (size_t)b * DIM * MODE;
#pragma unroll
        for (int mt = 0; mt < 4; ++mt)
#pragma unroll
            for (int nt = 0; nt < 2; ++nt)
#pragma unroll
                for (int r = 0; r < 4; ++r)
                    atomicAdd(yb + (size_t)(mt * 16 + quad * 4 + r) * 128 + k_base + nt * 16 + l16,
                              acc[mt][nt][r]);
    }
}

// A buffer in FRAG-MAJOR layout (y|Wconv, single bf16 plane).  grid (32) x 256
__global__ __launch_bounds__(256) void k_build_A(
        const float* __restrict__ y, const float* __restrict__ Wconv,
        u16* __restrict__ Ah, int lay) {
    int b = blockIdx.x;
    for (int idx = threadIdx.x; idx < 12288; idx += 256) {
        int i = idx & 7, l16 = (idx >> 3) & 15, quad = (idx >> 7) & 3,
            ot = (idx >> 9) & 3, ks = idx >> 11;
        int o = ot * 16 + l16;
        int k = ks * 32 + quad * 8 + i;
        float v = (k < 128) ? y[((size_t)b * DIM + o) * MODE + k]
                            : Wconv[(size_t)lay * DIM * DIM + o * DIM + (k - 128)];
        Ah[(size_t)b * 12288 + idx] = to_bf16(v);
    }
}

// ---------------------------------------------------------------------------
// inv_conv: h' = act(A(64x192) @ B(192 x 128x) + bconv), in-place on h.
// DO_MLP (compile-time): lay2 computes final MLP from LDS tile, skips
// writeback.  grid (32 b, 128 xt) x 256 (4 waves; wave = 64o x 32x).
#define CPAD 72
template <bool DO_MLP>
__global__ __launch_bounds__(256, 4) void k_inv_conv_mfma(
        const u16* __restrict__ Afh,
        const u16* __restrict__ Bfh,
        u16* __restrict__ Hh,
        const float* __restrict__ bconv, int lay,
        const u16* __restrict__ W1h,
        const float* __restrict__ b1, const float* __restrict__ W2,
        const float* __restrict__ b2, float* __restrict__ out) {
    __shared__ u16 hsh[128 * CPAD];
    int t = threadIdx.x;
    int wave = t >> 6, lane = t & 63, quad = lane >> 4, l16 = lane & 15;
    int b = blockIdx.x;
    int x0 = blockIdx.y * 128;
#pragma unroll
    for (int it = 0; it < 4; ++it) {
        int idx = it * 256 + t;
        int row = idx >> 3, c8 = (idx & 7) * 8;
        size_t src = ((size_t)(b << 14) + x0 + row) * 64 + c8;
        *(bf16x8*)&hsh[row * CPAD + c8] = *(const bf16x8*)(Hh + src);
    }
    __syncthreads();

    int xw = wave * 32;
    const u16* afb_h = Afh + (size_t)b * 12288;
    f32x4 acc[4][2] = {};
#pragma unroll
    for (int ks = 0; ks < 6; ++ks) {
        bf16x8 afh[4], bfh[2];
#pragma unroll
        for (int ot = 0; ot < 4; ++ot) {
            size_t ao = (size_t)(((ks * 4 + ot) * 4 + quad) * 16 + l16) * 8;
            afh[ot] = *(const bf16x8*)(afb_h + ao);
        }
#pragma unroll
        for (int x2 = 0; x2 < 2; ++x2) {
            int xl = xw + x2 * 16 + l16;
            if (ks < 4) {
                size_t bo = (size_t)((ks * 4 + quad) * 16384 + x0 + xl) * 8;
                bfh[x2] = *(const bf16x8*)(Bfh + bo);
            } else {
                int ko = (ks - 4) * 32 + quad * 8;
                bfh[x2] = *(const bf16x8*)&hsh[xl * CPAD + ko];
            }
        }
#pragma unroll
        for (int ot = 0; ot < 4; ++ot)
#pragma unroll
            for (int x2 = 0; x2 < 2; ++x2)
                acc[ot][x2] = __builtin_amdgcn_mfma_f32_16x16x32_bf16(afh[ot], bfh[x2], acc[ot][x2], 0, 0, 0);
    }
    __syncthreads();   // all LDS h reads done -> reuse hsh for C staging

#pragma unroll
    for (int ot = 0; ot < 4; ++ot) {
        float4 bc = *(const float4*)(bconv + lay * DIM + ot * 16 + quad * 4);
#pragma unroll
        for (int x2 = 0; x2 < 2; ++x2) {
            int xl = xw + x2 * 16 + l16;
            float vr[4] = {acc[ot][x2][0] + bc.x, acc[ot][x2][1] + bc.y,
                           acc[ot][x2][2] + bc.z, acc[ot][x2][3] + bc.w};
            if (!DO_MLP) {
#pragma unroll
                for (int r = 0; r < 4; ++r) vr[r] = gelu_fast(vr[r]);
            }
            ushort4 uh;
            uh.x = to_bf16(vr[0]); uh.y = to_bf16(vr[1]);
            uh.z = to_bf16(vr[2]); uh.w = to_bf16(vr[3]);
            *(ushort4*)&hsh[xl * CPAD + ot * 16 + quad * 4] = uh;
        }
    }
    __syncthreads();

    if (!DO_MLP) {
#pragma unroll
        for (int it = 0; it < 4; ++it) {
            int idx = it * 256 + t;
            int row = idx >> 3, c8 = (idx & 7) * 8;
            size_t dst = ((size_t)(b << 14) + x0 + row) * 64 + c8;
            *(bf16x8*)(Hh + dst) = *(const bf16x8*)&hsh[row * CPAD + c8];
        }
        return;
    }

    // ---- fused final MLP (lay 2 only): out = gelu(h'@W1+b1)@W2 + b2 ----
#pragma unroll
    for (int x2 = 0; x2 < 2; ++x2) {
        bf16x8 ah[2];
#pragma unroll
        for (int ks = 0; ks < 2; ++ks) {
            int ro = (xw + x2 * 16 + l16) * CPAD + ks * 32 + quad * 8;
            ah[ks] = *(const bf16x8*)&hsh[ro];
        }
        float vo[4] = {0.f, 0.f, 0.f, 0.f};
#pragma unroll
        for (int ft = 0; ft < 8; ++ft) {
            f32x4 a2 = {};
#pragma unroll
            for (int ks = 0; ks < 2; ++ks) {
                size_t o = (size_t)(ft * 16 + l16) * 64 + ks * 32 + quad * 8;
                bf16x8 bh = *(const bf16x8*)(W1h + o);
                a2 = __builtin_amdgcn_mfma_f32_16x16x32_bf16(ah[ks], bh, a2, 0, 0, 0);
            }
            float bb = b1[ft * 16 + l16];
            float w2 = W2[ft * 16 + l16];
#pragma unroll
            for (int r = 0; r < 4; ++r)
                vo[r] += gelu_fast(a2[r] + bb) * w2;
        }
#pragma unroll
        for (int r = 0; r < 4; ++r) {
            float v = vo[r];
            v += __shfl_xor(v, 1);
            v += __shfl_xor(v, 2);
            v += __shfl_xor(v, 4);
            v += __shfl_xor(v, 8);
            vo[r] = v;
        }
        if (l16 == 0) {
            float bb2 = b2[0];
            float4 o4 = make_float4(vo[0] + bb2, vo[1] + bb2, vo[2] + bb2, vo[3] + bb2);
            *(float4*)(out + (size_t)b * NXX + x0 + xw + x2 * 16 + quad * 4) = o4;
        }
    }
}

// ---------------------------------------------------------------------------
extern "C" void kernel_launch(void* const* d_in, const int* in_sizes, int n_in,
                              void* d_out, int out_size, void* d_ws, size_t ws_size,
                              hipStream_t stream) {
    const float* x      = (const float*)d_in[0];
    const float* bases  = (const float*)d_in[1];
    const float* wbases = (const float*)d_in[2];
    const float* product= (const float*)d_in[3];
    const float* Dout   = (const float*)d_in[4];
    const float* Din    = (const float*)d_in[5];
    const float* A      = (const float*)d_in[6];
    const float* Bm     = (const float*)d_in[7];
    const float* Wsp    = (const float*)d_in[8];
    const float* Wconv  = (const float*)d_in[9];
    const float* bconv  = (const float*)d_in[10];
    const float* W0     = (const float*)d_in[11];
    const float* b0     = (const float*)d_in[12];
    const float* W1     = (const float*)d_in[13];
    const float* b1     = (const float*)d_in[14];
    const float* W2     = (const float*)d_in[15];
    const float* b2     = (const float*)d_in[16];
    float* out = (float*)d_out;

    const size_t need = 79314944;
    if (ws_size < need) {
        k_zero<<<dim3((out_size + 255) / 256), dim3(256), 0, stream>>>(out, out_size);
        return;
    }

    char* W = (char*)d_ws;
    size_t off = 0;
    auto alloc = [&](size_t bytes) { void* p = W + off; off += bytes; return p; };
    u16*   Hbf      = (u16*)alloc(524288);
    u16*   WsT      = (u16*)alloc(393216);
    u16*   bases_hi = (u16*)alloc(4194304);
    u16*   wbT_hi   = (u16*)alloc(4194304);
    u16*   Abuf_hi  = (u16*)alloc(786432);
    float* ybuf     = (float*)alloc(1048576);
    float* xh       = (float*)alloc(1048576);   // must follow ybuf (joint zeroing)
    u16*   h_hi     = (u16*)alloc(67108864);
    u16*   w1t_hi   = (u16*)alloc(16384);

    k_build_H<<<dim3(1024), dim3(256), 0, stream>>>(Dout, Din, product, A, Bm, Hbf);
    k_setup_wst<<<dim3(768), dim3(256), 0, stream>>>(Wsp, WsT);
    k_setup_bases<<<dim3(8192), dim3(256), 0, stream>>>(bases, bases_hi);
    k_setup_wbT<<<dim3(512, 4), dim3(256), 0, stream>>>(wbases, wbT_hi);
    k_setup_w1t<<<dim3(32), dim3(256), 0, stream>>>(W1, w1t_hi);
    k_fc0<<<dim3(512, B_SZ), dim3(256), 0, stream>>>(x, W0, b0, h_hi);

    for (int lay = 0; lay < N_LAY; ++lay) {
        int last = (lay == N_LAY - 1);
        k_zero<<<dim3(2048), dim3(256), 0, stream>>>(ybuf, 524288);  // ybuf + xh
        k_spectral_mfma<<<dim3(B_SZ, 32), dim3(256), 0, stream>>>(
            h_hi, wbT_hi, xh);
        k_hmix_mfma<<<dim3(B_SZ, JM), dim3(256), 0, stream>>>(
            xh, Hbf, WsT, ybuf, lay);
        k_build_A<<<dim3(B_SZ), dim3(256), 0, stream>>>(ybuf, Wconv, Abuf_hi, lay);
        dim3 g(B_SZ, 128), blk(256);
        if (last)
            k_inv_conv_mfma<true><<<g, blk, 0, stream>>>(
                Abuf_hi, bases_hi, h_hi, bconv, lay,
                w1t_hi, b1, W2, b2, out);
        else
            k_inv_conv_mfma<false><<<g, blk, 0, stream>>>(
                Abuf_hi, bases_hi, h_hi, bconv, lay,
                w1t_hi, b1, W2, b2, out);
    }
}